// Round 6
// baseline (602.207 us; speedup 1.0000x reference)
//
#include <hip/hip_runtime.h>
#include <hip/hip_bf16.h>

#define N_NODES 20000
#define N_EDGES 100000
#define N_LAYERS 25
#define NPAD 20096   // 157*128
#define EPS_BN 1e-5f
#define LOG2E 1.44269504088896340736f
#define NL_NN (N_LAYERS * N_NODES)          // 500000
#define TOTAL_E (N_LAYERS * N_EDGES)        // 2500000
#define TOTAL_SLOTS (TOTAL_E + NL_NN)       // 3000000 (cnt+1 slots per node)
#define SCAN_BLKS ((NL_NN + 1023) / 1024)   // 489
#define QUARTER_N 5000
#define CNT_BLKS (N_LAYERS * 4)             // 100
#define W1T_END (CNT_BLKS + 700)            // 800
#define XPAD_END (W1T_END + 157)            // 957
#define HPAD_BLKS 75                        // 25*96*32 shorts / 1024
#define PREP_BLKS (XPAD_END + HPAD_BLKS)    // 1032
#define EDGE_BLKS ((TOTAL_E + 1023) / 1024) // 2442
#define FILL_BLKS (EDGE_BLKS + SCAN_BLKS)
#define NPW 8                               // nodes per wave
#define NPL (N_NODES / NPW)                 // 2500 waves per layer
#define ATTN_WAVES (NL_NN / NPW)            // 62500
#define ATTN_BLKS (ATTN_WAVES / 4)          // 15625

typedef short short8 __attribute__((ext_vector_type(8)));
typedef short short4v __attribute__((ext_vector_type(4)));
typedef float floatx4 __attribute__((ext_vector_type(4)));
typedef float float8v __attribute__((ext_vector_type(8)));
typedef int int8v __attribute__((ext_vector_type(8)));
typedef int int2v __attribute__((ext_vector_type(2)));

template <int PAT>
__device__ __forceinline__ float swz(float v) {
  return __int_as_float(__builtin_amdgcn_ds_swizzle(__float_as_int(v), PAT));
}

template <int CTRL>
__device__ __forceinline__ float dpp_add(float v) {
  int r = __builtin_amdgcn_update_dpp(0, __float_as_int(v), CTRL, 0xF, 0xF, true);
  return v + __int_as_float(r);
}

// int index on purpose: 32-bit address math
__device__ __forceinline__ float ldbf(const unsigned short* __restrict__ p, int idx) {
  return __uint_as_float((unsigned)p[idx] << 16);
}

__device__ __forceinline__ unsigned short bfbits(float v) {
  return __builtin_bit_cast(unsigned short, (__hip_bfloat16)v);
}

// async global->LDS, 16B per lane; LDS dest = wave-uniform base + lane*16
__device__ __forceinline__ void gl_lds16(const short* g, short* l) {
  __builtin_amdgcn_global_load_lds(
      (const __attribute__((address_space(1))) void*)g,
      (__attribute__((address_space(3))) void*)l, 16, 0, 0);
}

// scalar load of one 32B record + wait (single asm: wait inseparable)
__device__ __forceinline__ int8v sload8(const void* p) {
  int8v r;
  asm volatile(
      "s_load_dwordx8 %0, %1, 0x0\n\t"
      "s_waitcnt lgkmcnt(0)"
      : "=s"(r)
      : "s"(p));
  return r;
}

// scalar load of 16 ints (two dwordx8, 32B-aligned) + wait
__device__ __forceinline__ void sload_rp(const void* p, int8v& a, int8v& b) {
  asm volatile(
      "s_load_dwordx8 %0, %2, 0x0\n\t"
      "s_load_dwordx8 %1, %2, 0x20\n\t"
      "s_waitcnt lgkmcnt(0)"
      : "=s"(a), "=s"(b)
      : "s"(p));
}

// scalar load of a 4-record chunk (128B) in one block; single wait
__device__ __forceinline__ void sload_chunk(const void* p, int8v& r0, int8v& r1,
                                            int8v& r2, int8v& r3) {
  asm volatile(
      "s_load_dwordx8 %0, %4, 0x0\n\t"
      "s_load_dwordx8 %1, %4, 0x20\n\t"
      "s_load_dwordx8 %2, %4, 0x40\n\t"
      "s_load_dwordx8 %3, %4, 0x60\n\t"
      "s_waitcnt lgkmcnt(0)"
      : "=s"(r0), "=s"(r1), "=s"(r2), "=s"(r3)
      : "s"(p));
}

// 4-chain interleaved 16-lane reduce: single-instruction DPP adds.
// 4-way interleave gives 3-instr gaps (>=2 wait states VALU->DPP);
// s_nop 1 guards asm entry/exit adjacency.
__device__ __forceinline__ void red4(float& p0, float& p1, float& p2, float& p3) {
  asm volatile(
      "s_nop 1\n\t"
      "v_add_f32_dpp %0, %0, %0 quad_perm:[1,0,3,2] row_mask:0xf bank_mask:0xf\n\t"
      "v_add_f32_dpp %1, %1, %1 quad_perm:[1,0,3,2] row_mask:0xf bank_mask:0xf\n\t"
      "v_add_f32_dpp %2, %2, %2 quad_perm:[1,0,3,2] row_mask:0xf bank_mask:0xf\n\t"
      "v_add_f32_dpp %3, %3, %3 quad_perm:[1,0,3,2] row_mask:0xf bank_mask:0xf\n\t"
      "v_add_f32_dpp %0, %0, %0 quad_perm:[2,3,0,1] row_mask:0xf bank_mask:0xf\n\t"
      "v_add_f32_dpp %1, %1, %1 quad_perm:[2,3,0,1] row_mask:0xf bank_mask:0xf\n\t"
      "v_add_f32_dpp %2, %2, %2 quad_perm:[2,3,0,1] row_mask:0xf bank_mask:0xf\n\t"
      "v_add_f32_dpp %3, %3, %3 quad_perm:[2,3,0,1] row_mask:0xf bank_mask:0xf\n\t"
      "v_add_f32_dpp %0, %0, %0 row_half_mirror row_mask:0xf bank_mask:0xf\n\t"
      "v_add_f32_dpp %1, %1, %1 row_half_mirror row_mask:0xf bank_mask:0xf\n\t"
      "v_add_f32_dpp %2, %2, %2 row_half_mirror row_mask:0xf bank_mask:0xf\n\t"
      "v_add_f32_dpp %3, %3, %3 row_half_mirror row_mask:0xf bank_mask:0xf\n\t"
      "v_add_f32_dpp %0, %0, %0 row_mirror row_mask:0xf bank_mask:0xf\n\t"
      "v_add_f32_dpp %1, %1, %1 row_mirror row_mask:0xf bank_mask:0xf\n\t"
      "v_add_f32_dpp %2, %2, %2 row_mirror row_mask:0xf bank_mask:0xf\n\t"
      "v_add_f32_dpp %3, %3, %3 row_mirror row_mask:0xf bank_mask:0xf\n\t"
      "s_nop 1"
      : "+v"(p0), "+v"(p1), "+v"(p2), "+v"(p3));
}

// --- prep: count hist (rank + wsum capture) + W1^T + xpad + hn pad zero -----
__global__ __launch_bounds__(1024) void prep_kernel(
    const int* __restrict__ ei, const float* __restrict__ ew,
    const float* __restrict__ x, const float* __restrict__ W1,
    int* __restrict__ cnt, int* __restrict__ rank,
    float* __restrict__ wsumg, float* __restrict__ xpad,
    __hip_bfloat16* __restrict__ W1bT, unsigned short* __restrict__ hn) {
  __shared__ int smem[QUARTER_N];    // count hist; W1T reuses as float tile
  __shared__ float fsm[QUARTER_N];   // weight sums
  int b = blockIdx.x;
  if (b < CNT_BLKS) {
    int l = b >> 2, base = (b & 3) * QUARTER_N;
    for (int i = threadIdx.x; i < QUARTER_N; i += 1024) {
      smem[i] = 0;
      fsm[i] = 0.f;
    }
    __syncthreads();
    const int* dstp = ei + (size_t)l * 2 * N_EDGES + N_EDGES;
    const float* ewp = ew + (size_t)l * N_EDGES;
    int* rkp = rank + l * N_EDGES;
    for (int e = threadIdx.x; e < N_EDGES; e += 1024) {
      int d = dstp[e] - base;
      if ((unsigned)d < (unsigned)QUARTER_N) {
        rkp[e] = atomicAdd(&smem[d], 1);
        atomicAdd(&fsm[d], ewp[e]);
      }
    }
    __syncthreads();
    int* outp = cnt + l * N_NODES + base;
    float* wp = wsumg + l * N_NODES + base;
    for (int i = threadIdx.x; i < QUARTER_N; i += 1024) {
      outp[i] = smem[i];
      wp[i] = fsm[i];
    }
  } else if (b < W1T_END) {
    float* tile = (float*)smem;  // [32][33]
    int bb = b - CNT_BLKS;
    int j0 = (bb % 28) * 32, k0 = (bb / 28) * 32;
    int tx = threadIdx.x & 31, ty = threadIdx.x >> 5;
    tile[ty * 33 + tx] = (j0 + tx < 800) ? W1[(k0 + ty) * 800 + j0 + tx] : 0.f;
    __syncthreads();
    W1bT[(size_t)(j0 + ty) * 800 + k0 + tx] = (__hip_bfloat16)tile[tx * 33 + ty];
  } else if (b < XPAD_END) {
    int idx = (b - W1T_END) * 1024 + threadIdx.x;
    if (idx < N_NODES * 8) {
      int nn = idx >> 3, k = idx & 7;
      xpad[idx] = (k < 5) ? x[nn * 5 + k] : 0.f;
    }
  } else {
    // zero hn pad rows (N_NODES..NPAD) so gemm1 reads finite values
    int idx = (b - XPAD_END) * 1024 + threadIdx.x;
    const int per_l = (NPAD - N_NODES) * 32;  // 3072
    if (idx < N_LAYERS * per_l) {
      int l = idx / per_l;
      int rem = idx - l * per_l;
      hn[((size_t)l * NPAD + N_NODES) * 32 + rem] = 0;
    }
  }
}

// -------- scan_a: per-block scan over (cnt+1) slots; zero gsum/gsumsq -------
__global__ __launch_bounds__(1024) void scan_a(const int* __restrict__ cnt,
                                               int* __restrict__ scn,
                                               int* __restrict__ btot,
                                               float* __restrict__ gsum,
                                               float* __restrict__ gsumsq) {
  int t = threadIdx.x, b = blockIdx.x;
  int i = b * 1024 + t;
  int lane = t & 63, wv = t >> 6;
  int v = (i < NL_NN) ? cnt[i] + 1 : 0;  // +1: inline self-loop slot
  int sc = v;
#pragma unroll
  for (int off = 1; off < 64; off <<= 1) {
    int u = __shfl_up(sc, off);
    if (lane >= off) sc += u;
  }
  __shared__ int ws[16];
  if (lane == 63) ws[wv] = sc;
  __syncthreads();
  if (t < 16) {
    int xx = ws[t];
#pragma unroll
    for (int off = 1; off < 16; off <<= 1) {
      int u = __shfl_up(xx, off);
      if (t >= off) xx += u;
    }
    ws[t] = xx;
  }
  __syncthreads();
  int bofs = wv ? ws[wv - 1] : 0;
  if (i < NL_NN) scn[i] = bofs + sc - v;
  if (t == 0) btot[b] = ws[15];
  if (b == 200 && t < N_LAYERS * 32) {
    gsum[t] = 0.f;
    gsumsq[t] = 0.f;
  }
}

__global__ __launch_bounds__(512) void scan_b(const int* __restrict__ btot,
                                              int* __restrict__ boff) {
  int t = threadIdx.x;
  int lane = t & 63, wv = t >> 6;
  int v = (t < SCAN_BLKS) ? btot[t] : 0;
  int sc = v;
#pragma unroll
  for (int off = 1; off < 64; off <<= 1) {
    int u = __shfl_up(sc, off);
    if (lane >= off) sc += u;
  }
  __shared__ int ws[8];
  if (lane == 63) ws[wv] = sc;
  __syncthreads();
  if (t < 8) {
    int xx = ws[t];
#pragma unroll
    for (int off = 1; off < 8; off <<= 1) {
      int u = __shfl_up(xx, off);
      if (t >= off) xx += u;
    }
    ws[t] = xx;
  }
  __syncthreads();
  int bofs = wv ? ws[wv - 1] : 0;
  if (t < SCAN_BLKS) boff[t] = bofs + sc - v;
}

// ------- fill: edge-parallel; 32B records {w, x0..x4, 0, 0} -----------------
// tail: builds rowptr AND appends the self-loop record per node at slot cnt
// (w = mean incoming weight, x = own node's x) so attn has no self tail.
__global__ __launch_bounds__(1024) void fill_kernel(const int* __restrict__ ei,
                                                    const float* __restrict__ ew,
                                                    const int* __restrict__ scn,
                                                    const int* __restrict__ boff,
                                                    const int* __restrict__ rank,
                                                    const float* __restrict__ wsumg,
                                                    const float* __restrict__ xpad,
                                                    int* __restrict__ rowptr,
                                                    float* __restrict__ epf) {
  int b = blockIdx.x;
  if (b < EDGE_BLKS) {
    int idx = b * 1024 + threadIdx.x;
    if (idx >= TOTAL_E) return;
    int l = idx / N_EDGES, e = idx - l * N_EDGES;
    int src = ei[(size_t)l * 2 * N_EDGES + e];
    int dst = ei[(size_t)l * 2 * N_EDGES + N_EDGES + e];
    int g = l * N_NODES + dst;
    int pos = scn[g] + boff[g >> 10] + rank[idx];
    float w = ew[(size_t)l * N_EDGES + e];
    float4 xv = *(const float4*)(xpad + (size_t)src * 8);
    float x4v = xpad[(size_t)src * 8 + 4];
    float8v r;
    r[0] = w; r[1] = xv.x; r[2] = xv.y; r[3] = xv.z; r[4] = xv.w; r[5] = x4v;
    r[6] = 0.f; r[7] = 0.f;
    *(float8v*)(epf + (size_t)pos * 8) = r;
  } else {
    int i = (b - EDGE_BLKS) * 1024 + threadIdx.x;
    if (i < NL_NN) {
      int st = scn[i] + boff[i >> 10];
      int en = (i + 1 < NL_NN) ? scn[i + 1] + boff[(i + 1) >> 10] : TOTAL_SLOTS;
      rowptr[i] = st;
      int cw = en - st - 1;  // real incoming-edge count
      float wm = wsumg[i] * __builtin_amdgcn_rcpf(fmaxf((float)cw, 1.f));
      int n = i - (i / N_NODES) * N_NODES;
      float4 xv = *(const float4*)(xpad + (size_t)n * 8);
      float x4v = xpad[(size_t)n * 8 + 4];
      float8v r;
      r[0] = wm; r[1] = xv.x; r[2] = xv.y; r[3] = xv.z; r[4] = xv.w; r[5] = x4v;
      r[6] = 0.f; r[7] = 0.f;
      *(float8v*)(epf + (size_t)(en - 1) * 8) = r;  // self record at slot cnt
    }
    if (i < 31) rowptr[NL_NN + i] = TOTAL_SLOTS;  // sentinel + OOB-read pad
    if (i < 4) {
      float8v z = {0.f, 0.f, 0.f, 0.f, 0.f, 0.f, 0.f, 0.f};
      *(float8v*)(epf + (size_t)(TOTAL_SLOTS + i) * 8) = z;
    }
  }
}

// ---------------- fused GAT layer: 1 wave per 8 (layer,node)s ----------------
// Self-loop rides in the record stream (appended by fill), so the inner loop
// is uniform: chunk sload -> 5-FMA reconstruct -> score -> DPP reduce -> exp.
// Masking of tail pad slots is a single post-exp cndmask (garbage-safe).
__global__ __launch_bounds__(256) void attn_kernel(
    const float* __restrict__ xpad, const int* __restrict__ rowptr,
    const float* __restrict__ epf,
    const float* __restrict__ Wl, const float* __restrict__ bl,
    const float* __restrict__ Wr, const float* __restrict__ br,
    const float* __restrict__ We, const float* __restrict__ att,
    const float* __restrict__ cbias, unsigned short* __restrict__ out_pre) {
  int b = blockIdx.x;
  // m204 bijective XCD swizzle (ATTN_BLKS % 8 != 0)
  const int q = ATTN_BLKS >> 3, r = ATTN_BLKS & 7;
  int xcd = b & 7, ib = b >> 3;
  int nb = (xcd < r ? xcd * (q + 1) : r * (q + 1) + (xcd - r) * q) + ib;
  // wave-uniform by construction; readfirstlane makes it SGPR for the compiler
  int wid = __builtin_amdgcn_readfirstlane(nb * 4 + (threadIdx.x >> 6));
  int lane = threadIdx.x & 63;
  int l = wid / NPL;
  int n0 = (wid - l * NPL) * NPW;

  // layer params, once per wave (L1/L2-hot)
  float wlv0 = Wl[(l * 5 + 0) * 64 + lane];
  float wlv1 = Wl[(l * 5 + 1) * 64 + lane];
  float wlv2 = Wl[(l * 5 + 2) * 64 + lane];
  float wlv3 = Wl[(l * 5 + 3) * 64 + lane];
  float wlv4 = Wl[(l * 5 + 4) * 64 + lane];
  float wr0 = Wr[(l * 5 + 0) * 64 + lane];
  float wr1 = Wr[(l * 5 + 1) * 64 + lane];
  float wr2 = Wr[(l * 5 + 2) * 64 + lane];
  float wr3 = Wr[(l * 5 + 3) * 64 + lane];
  float wr4 = Wr[(l * 5 + 4) * 64 + lane];
  float blv = bl[l * 64 + lane];
  float brv = br[l * 64 + lane];
  float wev = We[l * 64 + lane];
  float att2v = att[l * 64 + lane] * LOG2E;
  float cbv = cbias[l * 32 + (lane & 31)];

  // 9 CSR slot offsets for this wave's 8 nodes
  int8v rpa, rpb;
  sload_rp(rowptr + (size_t)wid * 8, rpa, rpb);

#pragma unroll
  for (int i = 0; i < NPW; i++) {
    int st = rpa[i & 7];
    int en = (i == 7) ? rpb[0] : rpa[(i + 1) & 7];
    int valid = en - st;  // cnt+1 (self-loop inline), >= 1

    // dst transform from scalar x row (source transforms come from records)
    int8v xn = sload8(xpad + (size_t)(n0 + i) * 8);
    float xrn = brv;
    xrn = fmaf(__int_as_float(xn[0]), wr0, xrn);
    xrn = fmaf(__int_as_float(xn[1]), wr1, xrn);
    xrn = fmaf(__int_as_float(xn[2]), wr2, xrn);
    xrn = fmaf(__int_as_float(xn[3]), wr3, xrn);
    xrn = fmaf(__int_as_float(xn[4]), wr4, xrn);

    float ssum = 0.f, acc = 0.f;
    int nchunk = (valid + 3) >> 2;
    for (int c = 0; c < nchunk; c++) {
      int8v r0, r1, r2, r3;
      sload_chunk(epf + (size_t)(st + c * 4) * 8, r0, r1, r2, r3);
      int m = valid - c * 4;  // valid records this chunk
      float xa[4], pk[4];
#pragma unroll
      for (int k = 0; k < 4; k++) {
        int8v rr = (k == 0) ? r0 : (k == 1) ? r1 : (k == 2) ? r2 : r3;
        float a = fmaf(__int_as_float(rr[1]), wlv0, blv);
        a = fmaf(__int_as_float(rr[2]), wlv1, a);
        a = fmaf(__int_as_float(rr[3]), wlv2, a);
        a = fmaf(__int_as_float(rr[4]), wlv3, a);
        a = fmaf(__int_as_float(rr[5]), wlv4, a);
        xa[k] = a;
        float v = a + fmaf(__int_as_float(rr[0]), wev, xrn);
        float lk = fmaxf(v, 0.2f * v);
        pk[k] = lk * att2v;
      }
      red4(pk[0], pk[1], pk[2], pk[3]);
#pragma unroll
      for (int k = 0; k < 4; k++) pk[k] += swz<0x401F>(pk[k]);
#pragma unroll
      for (int k = 0; k < 4; k++) {
        float pe = __builtin_amdgcn_exp2f(pk[k]);
        pe = (k < m) ? pe : 0.f;  // pad-slot mask (garbage-safe post-exp)
        ssum += pe;
        acc = fmaf(xa[k], pe, acc);
      }
    }
    float outv = acc * __builtin_amdgcn_rcpf(ssum * (float)valid);
    float o2 = outv + __shfl_xor(outv, 32);
    if (lane < 32)
      out_pre[((size_t)wid * NPW + i) * 32 + lane] = bfbits(0.5f * o2 + cbv);
  }
}

// ---------------- BatchNorm stats (bf16 input) ----------------
__global__ __launch_bounds__(256) void stats_kernel(const unsigned short* __restrict__ out_pre,
                                                    float* __restrict__ gsum,
                                                    float* __restrict__ gsumsq) {
  int l = blockIdx.x >> 4, chunk = blockIdx.x & 15;
  int t = threadIdx.x;
  int c = t & 31, nsub = t >> 5;
  int n0 = chunk * 1250;
  float s1 = 0.f, s2 = 0.f;
  for (int n = n0 + nsub; n < n0 + 1250; n += 8) {
    float v = ldbf(out_pre, (l * N_NODES + n) * 32 + c);
    s1 += v; s2 += v * v;
  }
  __shared__ float l1[256], l2[256];
  l1[t] = s1; l2[t] = s2;
  __syncthreads();
  for (int off = 128; off >= 32; off >>= 1) {
    if (t < off) { l1[t] += l1[t + off]; l2[t] += l2[t + off]; }
    __syncthreads();
  }
  if (t < 32) {
    atomicAdd(&gsum[l * 32 + t], l1[t]);
    atomicAdd(&gsumsq[l * 32 + t], l2[t]);
  }
}

// ------- normalize + leaky relu -> bf16 [L][NPAD][32]; also init out=b2 -----
__global__ __launch_bounds__(256) void norm_kernel(const unsigned short* __restrict__ out_pre,
                                                   const float* __restrict__ gsum,
                                                   const float* __restrict__ gsumsq,
                                                   const float* __restrict__ gamma,
                                                   const float* __restrict__ beta,
                                                   const float* __restrict__ b2,
                                                   float* __restrict__ outg,
                                                   unsigned short* __restrict__ hn) {
  int idx = blockIdx.x * 256 + threadIdx.x;
  if (idx < N_NODES * 5) outg[idx] = b2[idx % 5];  // bias init for gemm1 atomics
  int l = idx / (N_NODES * 8);
  int rem = idx - l * (N_NODES * 8);
  int n = rem >> 3, q = rem & 7;
  int c0 = q * 4;
  short4v v4 = *(const short4v*)(out_pre + (l * N_NODES + n) * 32 + c0);
  short4v o;
#pragma unroll
  for (int i = 0; i < 4; i++) {
    int c = c0 + i;
    float mu = gsum[l * 32 + c] * (1.f / N_NODES);
    float var = gsumsq[l * 32 + c] * (1.f / N_NODES) - mu * mu;
    float vv = __uint_as_float((unsigned)(unsigned short)v4[i] << 16);
    float v = gamma[l * 32 + c] * (vv - mu) * rsqrtf(var + EPS_BN) + beta[l * 32 + c];
    v = v > 0.f ? v : 0.01f * v;
    o[i] = (short)bfbits(v);
  }
  *(short4v*)(hn + ((size_t)l * NPAD + n) * 32 + c0) = o;
}

// --- GEMM1: h @ W1 -> relu -> 5-dot with W2 -> atomicAdd into out -----------
// (gemm2r folded in: out pre-initialized to b2 by norm_kernel)
__global__ __launch_bounds__(256) void gemm1_kernel(const short* __restrict__ hn,
                                                    const short* __restrict__ W1bT,
                                                    const float* __restrict__ b1,
                                                    const float* __restrict__ W2,
                                                    float* __restrict__ outg) {
  __shared__ __align__(16) short As[128 * 32];
  __shared__ __align__(16) short Bs[128 * 32];
  int t = threadIdx.x;
  int n0 = blockIdx.x * 128, m0 = blockIdx.y * 128;
  int wave = t >> 6, lane = t & 63;
  int wr = wave >> 1, wc = wave & 1;
  int mrow = lane & 15, quad = lane >> 4;
  floatx4 acc[4][4];
#pragma unroll
  for (int i = 0; i < 4; i++)
#pragma unroll
    for (int j = 0; j < 4; j++) acc[i][j] = (floatx4){0.f, 0.f, 0.f, 0.f};

  int r0 = t >> 2, s0 = t & 3;
  int r1 = (t + 256) >> 2, s1 = (t + 256) & 3;
  const short* aG0 = hn + (m0 + r0) * 32 + s0 * 8;
  const short* aG1 = hn + (m0 + r1) * 32 + s1 * 8;
  const short* bG0 = W1bT + (n0 + r0) * 800 + s0 * 8;
  const short* bG1 = W1bT + (n0 + r1) * 800 + s1 * 8;
  const int ak = NPAD * 32;
  short* aD0 = As + wave * 512;
  short* aD1 = As + 2048 + wave * 512;
  short* bD0 = Bs + wave * 512;
  short* bD1 = Bs + 2048 + wave * 512;

  for (int kt = 0; kt < 25; kt++) {
    gl_lds16(aG0, aD0);
    gl_lds16(aG1, aD1);
    gl_lds16(bG0, bD0);
    gl_lds16(bG1, bD1);
    aG0 += ak; aG1 += ak; bG0 += 32; bG1 += 32;
    __syncthreads();
    short8 af[4], bfr[4];
#pragma unroll
    for (int i = 0; i < 4; i++)
      af[i] = *(const short8*)(&As[(wr * 64 + i * 16 + mrow) * 32 + quad * 8]);
#pragma unroll
    for (int j = 0; j < 4; j++)
      bfr[j] = *(const short8*)(&Bs[(wc * 64 + j * 16 + mrow) * 32 + quad * 8]);
#pragma unroll
    for (int i = 0; i < 4; i++)
#pragma unroll
      for (int j = 0; j < 4; j++)
        acc[i][j] = __builtin_amdgcn_mfma_f32_16x16x32_bf16(af[i], bfr[j], acc[i][j], 0, 0, 0);
    __syncthreads();
  }

  // epilogue: relu+bias, 5-dot with W2, 16-lane DPP reduce, atomic into out
  float w2v[4][5];
  float b1v[4];
#pragma unroll
  for (int j = 0; j < 4; j++) {
    int col = n0 + wc * 64 + j * 16 + mrow;
    bool ok = col < 800;
    b1v[j] = ok ? b1[col] : 0.f;
#pragma unroll
    for (int jj = 0; jj < 5; jj++) w2v[j][jj] = ok ? W2[col * 5 + jj] : 0.f;
  }
#pragma unroll
  for (int i = 0; i < 4; i++) {
#pragma unroll
    for (int r = 0; r < 4; r++) {
      float s[5] = {0.f, 0.f, 0.f, 0.f, 0.f};
#pragma unroll
      for (int j = 0; j < 4; j++) {
        float v = fmaxf(acc[i][j][r] + b1v[j], 0.f);
#pragma unroll
        for (int jj = 0; jj < 5; jj++) s[jj] = fmaf(v, w2v[j][jj], s[jj]);
      }
#pragma unroll
      for (int jj = 0; jj < 5; jj++) {
        s[jj] = dpp_add<0xB1>(s[jj]);
        s[jj] = dpp_add<0x4E>(s[jj]);
        s[jj] = dpp_add<0x141>(s[jj]);
        s[jj] = dpp_add<0x140>(s[jj]);
      }
      int row = m0 + wr * 64 + i * 16 + quad * 4 + r;
      if (mrow == 0 && row < N_NODES) {
#pragma unroll
        for (int jj = 0; jj < 5; jj++)
          atomicAdd(&outg[row * 5 + jj], s[jj]);
      }
    }
  }
}

extern "C" void kernel_launch(void* const* d_in, const int* in_sizes, int n_in,
                              void* d_out, int out_size, void* d_ws, size_t ws_size,
                              hipStream_t stream) {
  const float* x    = (const float*)d_in[0];
  const int*   ei   = (const int*)d_in[1];
  const float* ew   = (const float*)d_in[2];
  const float* Wl   = (const float*)d_in[3];
  const float* bl   = (const float*)d_in[4];
  const float* Wr   = (const float*)d_in[5];
  const float* br   = (const float*)d_in[6];
  const float* We   = (const float*)d_in[7];
  const float* att  = (const float*)d_in[8];
  const float* cb   = (const float*)d_in[9];
  const float* gam  = (const float*)d_in[10];
  const float* bet  = (const float*)d_in[11];
  const float* W1   = (const float*)d_in[12];
  const float* b1   = (const float*)d_in[13];
  const float* W2   = (const float*)d_in[14];
  const float* b2   = (const float*)d_in[15];

  char* ws = (char*)d_ws;
  size_t off = 0;
  auto alloc = [&](size_t bytes) {
    void* p = ws + off;
    off = (off + bytes + 255) & ~(size_t)255;
    return p;
  };
  int* cnt     = (int*)alloc((size_t)NL_NN * 4);
  int* scn     = (int*)alloc((size_t)NL_NN * 4);
  int* btot    = (int*)alloc(SCAN_BLKS * 4);
  int* boff    = (int*)alloc(SCAN_BLKS * 4);
  int* rank    = (int*)alloc((size_t)TOTAL_E * 4);
  int* rowptr  = (int*)alloc((size_t)(NL_NN + 32) * 4);
  float* wsumg = (float*)alloc((size_t)NL_NN * 4);
  float* epf   = (float*)alloc((size_t)TOTAL_SLOTS * 32 + 256);  // recs + pad
  unsigned short* out_pre = (unsigned short*)alloc((size_t)NL_NN * 32 * 2);
  float* gsum   = (float*)alloc(N_LAYERS * 32 * 4);
  float* gsumsq = (float*)alloc(N_LAYERS * 32 * 4);
  float* xpad   = (float*)alloc((size_t)N_NODES * 8 * 4);
  __hip_bfloat16* w1t = (__hip_bfloat16*)alloc((size_t)896 * 800 * 2);
  unsigned short* hn = (unsigned short*)alloc((size_t)N_LAYERS * NPAD * 32 * 2);

  prep_kernel<<<PREP_BLKS, 1024, 0, stream>>>(ei, ew, x, W1, cnt, rank, wsumg,
                                              xpad, w1t, hn);
  scan_a<<<SCAN_BLKS, 1024, 0, stream>>>(cnt, scn, btot, gsum, gsumsq);
  scan_b<<<1, 512, 0, stream>>>(btot, boff);
  fill_kernel<<<FILL_BLKS, 1024, 0, stream>>>(ei, ew, scn, boff, rank, wsumg,
                                              xpad, rowptr, epf);
  attn_kernel<<<ATTN_BLKS, 256, 0, stream>>>(
      xpad, rowptr, epf, Wl, bl, Wr, br, We, att, cb, out_pre);
  stats_kernel<<<N_LAYERS * 16, 256, 0, stream>>>(out_pre, gsum, gsumsq);
  norm_kernel<<<(NL_NN * 8) / 256, 256, 0, stream>>>(
      out_pre, gsum, gsumsq, gam, bet, b2, (float*)d_out, hn);
  gemm1_kernel<<<dim3(7, 157), 256, 0, stream>>>(
      (const short*)hn, (const short*)w1t, b1, W2, (float*)d_out);
}

// Round 7
// 484.303 us; speedup vs baseline: 1.2435x; 1.2435x over previous
//
#include <hip/hip_runtime.h>
#include <hip/hip_bf16.h>

#define N_NODES 20000
#define N_EDGES 100000
#define N_LAYERS 25
#define NPAD 20096   // 157*128
#define EPS_BN 1e-5f
#define LOG2E 1.44269504088896340736f
#define NL_NN (N_LAYERS * N_NODES)          // 500000
#define TOTAL_E (N_LAYERS * N_EDGES)        // 2500000
#define TOTAL_SLOTS (TOTAL_E + NL_NN)       // 3000000 (cnt+1 slots per node)
#define SCAN_BLKS ((NL_NN + 1023) / 1024)   // 489
#define QUARTER_N 5000
#define CNT_BLKS (N_LAYERS * 4)             // 100
#define W1T_END (CNT_BLKS + 700)            // 800
#define XPAD_END (W1T_END + 157)            // 957
#define HPAD_BLKS 75                        // 25*96*32 shorts / 1024
#define PREP_BLKS (XPAD_END + HPAD_BLKS)    // 1032
#define EDGE_BLKS ((TOTAL_E + 1023) / 1024) // 2442
#define FILL_BLKS (EDGE_BLKS + SCAN_BLKS)
#define NGRP 14                             // 7 col-tiles x 2 wc halves
#define NPW 8                               // nodes per wave
#define NPL (N_NODES / NPW)                 // 2500 waves per layer
#define ATTN_WAVES (NL_NN / NPW)            // 62500
#define ATTN_BLKS (ATTN_WAVES / 4)          // 15625
#define G1_BLKS (7 * 157)                   // 1099

typedef short short8 __attribute__((ext_vector_type(8)));
typedef short short4v __attribute__((ext_vector_type(4)));
typedef float floatx4 __attribute__((ext_vector_type(4)));
typedef float float8v __attribute__((ext_vector_type(8)));
typedef int int8v __attribute__((ext_vector_type(8)));
typedef int int2v __attribute__((ext_vector_type(2)));

template <int PAT>
__device__ __forceinline__ float swz(float v) {
  return __int_as_float(__builtin_amdgcn_ds_swizzle(__float_as_int(v), PAT));
}

template <int CTRL>
__device__ __forceinline__ float dpp_add(float v) {
  int r = __builtin_amdgcn_update_dpp(0, __float_as_int(v), CTRL, 0xF, 0xF, true);
  return v + __int_as_float(r);
}

// xor16 group-sum via VALU permlane16_swap (no LDS pipe); A=B=p makes the
// half-swap direction irrelevant: r0+r1 = sum of the two 16-lane halves of
// each 32-lane group, broadcast to all lanes. Fallback: ds_swizzle path.
__device__ __forceinline__ float xadd16(float p) {
#if __has_builtin(__builtin_amdgcn_permlane16_swap)
  int2v r = __builtin_amdgcn_permlane16_swap(__float_as_int(p),
                                             __float_as_int(p), false, false);
  return __int_as_float(r[0]) + __int_as_float(r[1]);
#else
  return p + swz<0x401F>(p);
#endif
}

// int index on purpose: 32-bit address math
__device__ __forceinline__ float ldbf(const unsigned short* __restrict__ p, int idx) {
  return __uint_as_float((unsigned)p[idx] << 16);
}

__device__ __forceinline__ unsigned short bfbits(float v) {
  return __builtin_bit_cast(unsigned short, (__hip_bfloat16)v);
}

// async global->LDS, 16B per lane; LDS dest = wave-uniform base + lane*16
__device__ __forceinline__ void gl_lds16(const short* g, short* l) {
  __builtin_amdgcn_global_load_lds(
      (const __attribute__((address_space(1))) void*)g,
      (__attribute__((address_space(3))) void*)l, 16, 0, 0);
}

// scalar load of one 32B record + wait (single asm: wait inseparable)
__device__ __forceinline__ int8v sload8(const void* p) {
  int8v r;
  asm volatile(
      "s_load_dwordx8 %0, %1, 0x0\n\t"
      "s_waitcnt lgkmcnt(0)"
      : "=s"(r)
      : "s"(p));
  return r;
}

// scalar load of 16 ints (two dwordx8, 32B-aligned) + wait
__device__ __forceinline__ void sload_rp(const void* p, int8v& a, int8v& b) {
  asm volatile(
      "s_load_dwordx8 %0, %2, 0x0\n\t"
      "s_load_dwordx8 %1, %2, 0x20\n\t"
      "s_waitcnt lgkmcnt(0)"
      : "=s"(a), "=s"(b)
      : "s"(p));
}

// scalar load of a 4-record chunk (128B) in one block; single wait
__device__ __forceinline__ void sload_chunk(const void* p, int8v& r0, int8v& r1,
                                            int8v& r2, int8v& r3) {
  asm volatile(
      "s_load_dwordx8 %0, %4, 0x0\n\t"
      "s_load_dwordx8 %1, %4, 0x20\n\t"
      "s_load_dwordx8 %2, %4, 0x40\n\t"
      "s_load_dwordx8 %3, %4, 0x60\n\t"
      "s_waitcnt lgkmcnt(0)"
      : "=s"(r0), "=s"(r1), "=s"(r2), "=s"(r3)
      : "s"(p));
}

// 4-chain interleaved 16-lane reduce: single-instruction DPP adds.
// 4-way interleave gives 3-instr gaps (>=2 wait states VALU->DPP);
// s_nop 1 guards asm entry/exit adjacency.
__device__ __forceinline__ void red4(float& p0, float& p1, float& p2, float& p3) {
  asm volatile(
      "s_nop 1\n\t"
      "v_add_f32_dpp %0, %0, %0 quad_perm:[1,0,3,2] row_mask:0xf bank_mask:0xf\n\t"
      "v_add_f32_dpp %1, %1, %1 quad_perm:[1,0,3,2] row_mask:0xf bank_mask:0xf\n\t"
      "v_add_f32_dpp %2, %2, %2 quad_perm:[1,0,3,2] row_mask:0xf bank_mask:0xf\n\t"
      "v_add_f32_dpp %3, %3, %3 quad_perm:[1,0,3,2] row_mask:0xf bank_mask:0xf\n\t"
      "v_add_f32_dpp %0, %0, %0 quad_perm:[2,3,0,1] row_mask:0xf bank_mask:0xf\n\t"
      "v_add_f32_dpp %1, %1, %1 quad_perm:[2,3,0,1] row_mask:0xf bank_mask:0xf\n\t"
      "v_add_f32_dpp %2, %2, %2 quad_perm:[2,3,0,1] row_mask:0xf bank_mask:0xf\n\t"
      "v_add_f32_dpp %3, %3, %3 quad_perm:[2,3,0,1] row_mask:0xf bank_mask:0xf\n\t"
      "v_add_f32_dpp %0, %0, %0 row_half_mirror row_mask:0xf bank_mask:0xf\n\t"
      "v_add_f32_dpp %1, %1, %1 row_half_mirror row_mask:0xf bank_mask:0xf\n\t"
      "v_add_f32_dpp %2, %2, %2 row_half_mirror row_mask:0xf bank_mask:0xf\n\t"
      "v_add_f32_dpp %3, %3, %3 row_half_mirror row_mask:0xf bank_mask:0xf\n\t"
      "v_add_f32_dpp %0, %0, %0 row_mirror row_mask:0xf bank_mask:0xf\n\t"
      "v_add_f32_dpp %1, %1, %1 row_mirror row_mask:0xf bank_mask:0xf\n\t"
      "v_add_f32_dpp %2, %2, %2 row_mirror row_mask:0xf bank_mask:0xf\n\t"
      "v_add_f32_dpp %3, %3, %3 row_mirror row_mask:0xf bank_mask:0xf\n\t"
      "s_nop 1"
      : "+v"(p0), "+v"(p1), "+v"(p2), "+v"(p3));
}

// --- prep: count hist (rank + wsum capture) + W1^T + xpad + hn pad zero -----
__global__ __launch_bounds__(1024) void prep_kernel(
    const int* __restrict__ ei, const float* __restrict__ ew,
    const float* __restrict__ x, const float* __restrict__ W1,
    int* __restrict__ cnt, int* __restrict__ rank,
    float* __restrict__ wsumg, float* __restrict__ xpad,
    __hip_bfloat16* __restrict__ W1bT, unsigned short* __restrict__ hn) {
  __shared__ int smem[QUARTER_N];    // count hist; W1T reuses as float tile
  __shared__ float fsm[QUARTER_N];   // weight sums
  int b = blockIdx.x;
  if (b < CNT_BLKS) {
    int l = b >> 2, base = (b & 3) * QUARTER_N;
    for (int i = threadIdx.x; i < QUARTER_N; i += 1024) {
      smem[i] = 0;
      fsm[i] = 0.f;
    }
    __syncthreads();
    const int* dstp = ei + (size_t)l * 2 * N_EDGES + N_EDGES;
    const float* ewp = ew + (size_t)l * N_EDGES;
    int* rkp = rank + l * N_EDGES;
    for (int e = threadIdx.x; e < N_EDGES; e += 1024) {
      int d = dstp[e] - base;
      if ((unsigned)d < (unsigned)QUARTER_N) {
        rkp[e] = atomicAdd(&smem[d], 1);
        atomicAdd(&fsm[d], ewp[e]);
      }
    }
    __syncthreads();
    int* outp = cnt + l * N_NODES + base;
    float* wp = wsumg + l * N_NODES + base;
    for (int i = threadIdx.x; i < QUARTER_N; i += 1024) {
      outp[i] = smem[i];
      wp[i] = fsm[i];
    }
  } else if (b < W1T_END) {
    float* tile = (float*)smem;  // [32][33]
    int bb = b - CNT_BLKS;
    int j0 = (bb % 28) * 32, k0 = (bb / 28) * 32;
    int tx = threadIdx.x & 31, ty = threadIdx.x >> 5;
    tile[ty * 33 + tx] = (j0 + tx < 800) ? W1[(k0 + ty) * 800 + j0 + tx] : 0.f;
    __syncthreads();
    W1bT[(size_t)(j0 + ty) * 800 + k0 + tx] = (__hip_bfloat16)tile[tx * 33 + ty];
  } else if (b < XPAD_END) {
    int idx = (b - W1T_END) * 1024 + threadIdx.x;
    if (idx < N_NODES * 8) {
      int nn = idx >> 3, k = idx & 7;
      xpad[idx] = (k < 5) ? x[nn * 5 + k] : 0.f;
    }
  } else {
    // zero hn pad rows (N_NODES..NPAD) so gemm1 reads finite values
    int idx = (b - XPAD_END) * 1024 + threadIdx.x;
    const int per_l = (NPAD - N_NODES) * 32;  // 3072
    if (idx < N_LAYERS * per_l) {
      int l = idx / per_l;
      int rem = idx - l * per_l;
      hn[((size_t)l * NPAD + N_NODES) * 32 + rem] = 0;
    }
  }
}

// -------- scan_a: per-block scan over (cnt+1) slots; zero gsum/gsumsq -------
__global__ __launch_bounds__(1024) void scan_a(const int* __restrict__ cnt,
                                               int* __restrict__ scn,
                                               int* __restrict__ btot,
                                               float* __restrict__ gsum,
                                               float* __restrict__ gsumsq) {
  int t = threadIdx.x, b = blockIdx.x;
  int i = b * 1024 + t;
  int lane = t & 63, wv = t >> 6;
  int v = (i < NL_NN) ? cnt[i] + 1 : 0;  // +1: inline self-loop slot
  int sc = v;
#pragma unroll
  for (int off = 1; off < 64; off <<= 1) {
    int u = __shfl_up(sc, off);
    if (lane >= off) sc += u;
  }
  __shared__ int ws[16];
  if (lane == 63) ws[wv] = sc;
  __syncthreads();
  if (t < 16) {
    int xx = ws[t];
#pragma unroll
    for (int off = 1; off < 16; off <<= 1) {
      int u = __shfl_up(xx, off);
      if (t >= off) xx += u;
    }
    ws[t] = xx;
  }
  __syncthreads();
  int bofs = wv ? ws[wv - 1] : 0;
  if (i < NL_NN) scn[i] = bofs + sc - v;
  if (t == 0) btot[b] = ws[15];
  if (b == 200 && t < N_LAYERS * 32) {
    gsum[t] = 0.f;
    gsumsq[t] = 0.f;
  }
}

__global__ __launch_bounds__(512) void scan_b(const int* __restrict__ btot,
                                              int* __restrict__ boff) {
  int t = threadIdx.x;
  int lane = t & 63, wv = t >> 6;
  int v = (t < SCAN_BLKS) ? btot[t] : 0;
  int sc = v;
#pragma unroll
  for (int off = 1; off < 64; off <<= 1) {
    int u = __shfl_up(sc, off);
    if (lane >= off) sc += u;
  }
  __shared__ int ws[8];
  if (lane == 63) ws[wv] = sc;
  __syncthreads();
  if (t < 8) {
    int xx = ws[t];
#pragma unroll
    for (int off = 1; off < 8; off <<= 1) {
      int u = __shfl_up(xx, off);
      if (t >= off) xx += u;
    }
    ws[t] = xx;
  }
  __syncthreads();
  int bofs = wv ? ws[wv - 1] : 0;
  if (t < SCAN_BLKS) boff[t] = bofs + sc - v;
}

// ------- fill: edge-parallel; 32B records {w, x0..x4, 0, 0} -----------------
// tail: builds rowptr AND appends the self-loop record per node at slot cnt
// (w = mean incoming weight, x = own node's x) so attn has no self tail.
__global__ __launch_bounds__(1024) void fill_kernel(const int* __restrict__ ei,
                                                    const float* __restrict__ ew,
                                                    const int* __restrict__ scn,
                                                    const int* __restrict__ boff,
                                                    const int* __restrict__ rank,
                                                    const float* __restrict__ wsumg,
                                                    const float* __restrict__ xpad,
                                                    int* __restrict__ rowptr,
                                                    float* __restrict__ epf) {
  int b = blockIdx.x;
  if (b < EDGE_BLKS) {
    int idx = b * 1024 + threadIdx.x;
    if (idx >= TOTAL_E) return;
    int l = idx / N_EDGES, e = idx - l * N_EDGES;
    int src = ei[(size_t)l * 2 * N_EDGES + e];
    int dst = ei[(size_t)l * 2 * N_EDGES + N_EDGES + e];
    int g = l * N_NODES + dst;
    int pos = scn[g] + boff[g >> 10] + rank[idx];
    float w = ew[(size_t)l * N_EDGES + e];
    float4 xv = *(const float4*)(xpad + (size_t)src * 8);
    float x4v = xpad[(size_t)src * 8 + 4];
    float8v r;
    r[0] = w; r[1] = xv.x; r[2] = xv.y; r[3] = xv.z; r[4] = xv.w; r[5] = x4v;
    r[6] = 0.f; r[7] = 0.f;
    *(float8v*)(epf + (size_t)pos * 8) = r;
  } else {
    int i = (b - EDGE_BLKS) * 1024 + threadIdx.x;
    if (i < NL_NN) {
      int st = scn[i] + boff[i >> 10];
      int en = (i + 1 < NL_NN) ? scn[i + 1] + boff[(i + 1) >> 10] : TOTAL_SLOTS;
      rowptr[i] = st;
      int cw = en - st - 1;  // real incoming-edge count
      float wm = wsumg[i] * __builtin_amdgcn_rcpf(fmaxf((float)cw, 1.f));
      int n = i - (i / N_NODES) * N_NODES;
      float4 xv = *(const float4*)(xpad + (size_t)n * 8);
      float x4v = xpad[(size_t)n * 8 + 4];
      float8v r;
      r[0] = wm; r[1] = xv.x; r[2] = xv.y; r[3] = xv.z; r[4] = xv.w; r[5] = x4v;
      r[6] = 0.f; r[7] = 0.f;
      *(float8v*)(epf + (size_t)(en - 1) * 8) = r;  // self record at slot cnt
    }
    if (i < 31) rowptr[NL_NN + i] = TOTAL_SLOTS;  // sentinel + OOB-read pad
    if (i < 4) {
      float8v z = {0.f, 0.f, 0.f, 0.f, 0.f, 0.f, 0.f, 0.f};
      *(float8v*)(epf + (size_t)(TOTAL_SLOTS + i) * 8) = z;
    }
  }
}

// ---------------- fused GAT layer: 1 wave per 8 (layer,node)s ----------------
// Self-loop rides in the record stream; xor16 broadcast is VALU permlane
// (no LDS-pipe latency). BatchNorm partial sums fused: 2 atomicAdds/wave.
__global__ __launch_bounds__(256) void attn_kernel(
    const float* __restrict__ xpad, const int* __restrict__ rowptr,
    const float* __restrict__ epf,
    const float* __restrict__ Wl, const float* __restrict__ bl,
    const float* __restrict__ Wr, const float* __restrict__ br,
    const float* __restrict__ We, const float* __restrict__ att,
    const float* __restrict__ cbias, unsigned short* __restrict__ out_pre,
    float* __restrict__ gsum, float* __restrict__ gsumsq) {
  int b = blockIdx.x;
  // m204 bijective XCD swizzle (ATTN_BLKS % 8 != 0)
  const int q = ATTN_BLKS >> 3, r = ATTN_BLKS & 7;
  int xcd = b & 7, ib = b >> 3;
  int nb = (xcd < r ? xcd * (q + 1) : r * (q + 1) + (xcd - r) * q) + ib;
  // wave-uniform by construction; readfirstlane makes it SGPR for the compiler
  int wid = __builtin_amdgcn_readfirstlane(nb * 4 + (threadIdx.x >> 6));
  int lane = threadIdx.x & 63;
  int l = wid / NPL;
  int n0 = (wid - l * NPL) * NPW;

  // layer params, once per wave (L1/L2-hot)
  float wlv0 = Wl[(l * 5 + 0) * 64 + lane];
  float wlv1 = Wl[(l * 5 + 1) * 64 + lane];
  float wlv2 = Wl[(l * 5 + 2) * 64 + lane];
  float wlv3 = Wl[(l * 5 + 3) * 64 + lane];
  float wlv4 = Wl[(l * 5 + 4) * 64 + lane];
  float wr0 = Wr[(l * 5 + 0) * 64 + lane];
  float wr1 = Wr[(l * 5 + 1) * 64 + lane];
  float wr2 = Wr[(l * 5 + 2) * 64 + lane];
  float wr3 = Wr[(l * 5 + 3) * 64 + lane];
  float wr4 = Wr[(l * 5 + 4) * 64 + lane];
  float blv = bl[l * 64 + lane];
  float brv = br[l * 64 + lane];
  float wev = We[l * 64 + lane];
  float att2v = att[l * 64 + lane] * LOG2E;
  float cbv = cbias[l * 32 + (lane & 31)];

  // 9 CSR slot offsets for this wave's 8 nodes
  int8v rpa, rpb;
  sload_rp(rowptr + (size_t)wid * 8, rpa, rpb);

  float s1 = 0.f, s2 = 0.f;  // BatchNorm partials (lanes<32 meaningful)

#pragma unroll
  for (int i = 0; i < NPW; i++) {
    int st = rpa[i & 7];
    int en = (i == 7) ? rpb[0] : rpa[(i + 1) & 7];
    int valid = en - st;  // cnt+1 (self-loop inline), >= 1

    // dst transform from scalar x row (source transforms come from records)
    int8v xn = sload8(xpad + (size_t)(n0 + i) * 8);
    float xrn = brv;
    xrn = fmaf(__int_as_float(xn[0]), wr0, xrn);
    xrn = fmaf(__int_as_float(xn[1]), wr1, xrn);
    xrn = fmaf(__int_as_float(xn[2]), wr2, xrn);
    xrn = fmaf(__int_as_float(xn[3]), wr3, xrn);
    xrn = fmaf(__int_as_float(xn[4]), wr4, xrn);

    float ssum = 0.f, acc = 0.f;
    int nchunk = (valid + 3) >> 2;
    for (int c = 0; c < nchunk; c++) {
      int8v r0, r1, r2, r3;
      sload_chunk(epf + (size_t)(st + c * 4) * 8, r0, r1, r2, r3);
      int m = valid - c * 4;  // valid records this chunk
      float xa[4], pk[4];
#pragma unroll
      for (int k = 0; k < 4; k++) {
        int8v rr = (k == 0) ? r0 : (k == 1) ? r1 : (k == 2) ? r2 : r3;
        float a = fmaf(__int_as_float(rr[1]), wlv0, blv);
        a = fmaf(__int_as_float(rr[2]), wlv1, a);
        a = fmaf(__int_as_float(rr[3]), wlv2, a);
        a = fmaf(__int_as_float(rr[4]), wlv3, a);
        a = fmaf(__int_as_float(rr[5]), wlv4, a);
        xa[k] = a;
        float v = a + fmaf(__int_as_float(rr[0]), wev, xrn);
        float lk = fmaxf(v, 0.2f * v);
        pk[k] = lk * att2v;
      }
      red4(pk[0], pk[1], pk[2], pk[3]);
#pragma unroll
      for (int k = 0; k < 4; k++) pk[k] = xadd16(pk[k]);
#pragma unroll
      for (int k = 0; k < 4; k++) {
        float pe = __builtin_amdgcn_exp2f(pk[k]);
        pe = (k < m) ? pe : 0.f;  // pad-slot mask (garbage-safe post-exp)
        ssum += pe;
        acc = fmaf(xa[k], pe, acc);
      }
    }
    float outv = acc * __builtin_amdgcn_rcpf(ssum * (float)valid);
    float o2 = outv + __shfl_xor(outv, 32);
    float oval = 0.5f * o2 + cbv;  // symmetric across lane^32
    if (lane < 32)
      out_pre[((size_t)wid * NPW + i) * 32 + lane] = bfbits(oval);
    s1 += oval;
    s2 = fmaf(oval, oval, s2);
  }
  if (lane < 32) {
    atomicAdd(&gsum[l * 32 + lane], s1);
    atomicAdd(&gsumsq[l * 32 + lane], s2);
  }
}

// ------- normalize + leaky relu -> bf16 [L][NPAD][32] -----------------------
__global__ __launch_bounds__(256) void norm_kernel(const unsigned short* __restrict__ out_pre,
                                                   const float* __restrict__ gsum,
                                                   const float* __restrict__ gsumsq,
                                                   const float* __restrict__ gamma,
                                                   const float* __restrict__ beta,
                                                   unsigned short* __restrict__ hn) {
  int idx = blockIdx.x * 256 + threadIdx.x;
  int l = idx / (N_NODES * 8);
  int rem = idx - l * (N_NODES * 8);
  int n = rem >> 3, q = rem & 7;
  int c0 = q * 4;
  short4v v4 = *(const short4v*)(out_pre + (l * N_NODES + n) * 32 + c0);
  short4v o;
#pragma unroll
  for (int i = 0; i < 4; i++) {
    int c = c0 + i;
    float mu = gsum[l * 32 + c] * (1.f / N_NODES);
    float var = gsumsq[l * 32 + c] * (1.f / N_NODES) - mu * mu;
    float vv = __uint_as_float((unsigned)(unsigned short)v4[i] << 16);
    float v = gamma[l * 32 + c] * (vv - mu) * rsqrtf(var + EPS_BN) + beta[l * 32 + c];
    v = v > 0.f ? v : 0.01f * v;
    o[i] = (short)bfbits(v);
  }
  *(short4v*)(hn + ((size_t)l * NPAD + n) * 32 + c0) = o;
}

// --- GEMM1: h @ W1 -> relu -> per-colgroup 5-dot partials (non-atomic) ------
// 1D grid + bijective XCD swizzle: each XCD owns a contiguous row-tile range,
// so its ~4MB hn slice stays L2-resident across the 7 column passes.
// each (row-tile, col-tile, wc) writes disjoint p[row][group][5].
__global__ __launch_bounds__(256) void gemm1_kernel(const short* __restrict__ hn,
                                                    const short* __restrict__ W1bT,
                                                    const float* __restrict__ b1,
                                                    const float* __restrict__ W2,
                                                    float* __restrict__ p) {
  __shared__ __align__(16) short As[128 * 32];
  __shared__ __align__(16) short Bs[128 * 32];
  const int q = G1_BLKS >> 3, r = G1_BLKS & 7;  // 137, 3
  int bf = blockIdx.x;
  int xcd = bf & 7, ib = bf >> 3;
  int nb = (xcd < r ? xcd * (q + 1) : r * (q + 1) + (xcd - r) * q) + ib;
  int mt = nb / 7, nt = nb - mt * 7;
  int n0 = nt * 128, m0 = mt * 128;
  int t = threadIdx.x;
  int wave = t >> 6, lane = t & 63;
  int wr = wave >> 1, wc = wave & 1;
  int mrow = lane & 15, quad = lane >> 4;
  floatx4 acc[4][4];
#pragma unroll
  for (int i = 0; i < 4; i++)
#pragma unroll
    for (int j = 0; j < 4; j++) acc[i][j] = (floatx4){0.f, 0.f, 0.f, 0.f};

  int r0 = t >> 2, s0 = t & 3;
  int r1 = (t + 256) >> 2, s1 = (t + 256) & 3;
  const short* aG0 = hn + (m0 + r0) * 32 + s0 * 8;
  const short* aG1 = hn + (m0 + r1) * 32 + s1 * 8;
  const short* bG0 = W1bT + (n0 + r0) * 800 + s0 * 8;
  const short* bG1 = W1bT + (n0 + r1) * 800 + s1 * 8;
  const int ak = NPAD * 32;
  short* aD0 = As + wave * 512;
  short* aD1 = As + 2048 + wave * 512;
  short* bD0 = Bs + wave * 512;
  short* bD1 = Bs + 2048 + wave * 512;

  for (int kt = 0; kt < 25; kt++) {
    gl_lds16(aG0, aD0);
    gl_lds16(aG1, aD1);
    gl_lds16(bG0, bD0);
    gl_lds16(bG1, bD1);
    aG0 += ak; aG1 += ak; bG0 += 32; bG1 += 32;
    __syncthreads();
    short8 af[4], bfr[4];
#pragma unroll
    for (int i = 0; i < 4; i++)
      af[i] = *(const short8*)(&As[(wr * 64 + i * 16 + mrow) * 32 + quad * 8]);
#pragma unroll
    for (int j = 0; j < 4; j++)
      bfr[j] = *(const short8*)(&Bs[(wc * 64 + j * 16 + mrow) * 32 + quad * 8]);
#pragma unroll
    for (int i = 0; i < 4; i++)
#pragma unroll
      for (int j = 0; j < 4; j++)
        acc[i][j] = __builtin_amdgcn_mfma_f32_16x16x32_bf16(af[i], bfr[j], acc[i][j], 0, 0, 0);
    __syncthreads();
  }

  // epilogue: relu+bias, 5-dot with W2, 16-lane DPP reduce, disjoint stores
  float w2v[4][5];
  float b1v[4];
#pragma unroll
  for (int j = 0; j < 4; j++) {
    int col = n0 + wc * 64 + j * 16 + mrow;
    bool ok = col < 800;
    b1v[j] = ok ? b1[col] : 0.f;
#pragma unroll
    for (int jj = 0; jj < 5; jj++) w2v[j][jj] = ok ? W2[col * 5 + jj] : 0.f;
  }
  int grp = nt * 2 + wc;
#pragma unroll
  for (int i = 0; i < 4; i++) {
#pragma unroll
    for (int rr = 0; rr < 4; rr++) {
      float s[5] = {0.f, 0.f, 0.f, 0.f, 0.f};
#pragma unroll
      for (int j = 0; j < 4; j++) {
        float v = fmaxf(acc[i][j][rr] + b1v[j], 0.f);
#pragma unroll
        for (int jj = 0; jj < 5; jj++) s[jj] = fmaf(v, w2v[j][jj], s[jj]);
      }
#pragma unroll
      for (int jj = 0; jj < 5; jj++) {
        s[jj] = dpp_add<0xB1>(s[jj]);
        s[jj] = dpp_add<0x4E>(s[jj]);
        s[jj] = dpp_add<0x141>(s[jj]);
        s[jj] = dpp_add<0x140>(s[jj]);
      }
      int row = m0 + wr * 64 + i * 16 + quad * 4 + rr;
      if (mrow == 0) {
#pragma unroll
        for (int jj = 0; jj < 5; jj++)
          p[(row * NGRP + grp) * 5 + jj] = s[jj];
      }
    }
  }
}

// ---- gemm2r: out[row][jj] = b2[jj] + sum_g p[row][g][jj] -------------------
__global__ __launch_bounds__(256) void gemm2r_kernel(const float* __restrict__ p,
                                                     const float* __restrict__ b2,
                                                     float* __restrict__ out) {
  int idx = blockIdx.x * 256 + threadIdx.x;
  if (idx >= N_NODES * 5) return;
  int row = idx / 5, jj = idx - row * 5;
  float s = b2[jj];
#pragma unroll
  for (int g = 0; g < NGRP; g++) s += p[(row * NGRP + g) * 5 + jj];
  out[idx] = s;
}

extern "C" void kernel_launch(void* const* d_in, const int* in_sizes, int n_in,
                              void* d_out, int out_size, void* d_ws, size_t ws_size,
                              hipStream_t stream) {
  const float* x    = (const float*)d_in[0];
  const int*   ei   = (const int*)d_in[1];
  const float* ew   = (const float*)d_in[2];
  const float* Wl   = (const float*)d_in[3];
  const float* bl   = (const float*)d_in[4];
  const float* Wr   = (const float*)d_in[5];
  const float* br   = (const float*)d_in[6];
  const float* We   = (const float*)d_in[7];
  const float* att  = (const float*)d_in[8];
  const float* cb   = (const float*)d_in[9];
  const float* gam  = (const float*)d_in[10];
  const float* bet  = (const float*)d_in[11];
  const float* W1   = (const float*)d_in[12];
  const float* b1   = (const float*)d_in[13];
  const float* W2   = (const float*)d_in[14];
  const float* b2   = (const float*)d_in[15];

  char* ws = (char*)d_ws;
  size_t off = 0;
  auto alloc = [&](size_t bytes) {
    void* p = ws + off;
    off = (off + bytes + 255) & ~(size_t)255;
    return p;
  };
  int* cnt     = (int*)alloc((size_t)NL_NN * 4);
  int* scn     = (int*)alloc((size_t)NL_NN * 4);
  int* btot    = (int*)alloc(SCAN_BLKS * 4);
  int* boff    = (int*)alloc(SCAN_BLKS * 4);
  int* rank    = (int*)alloc((size_t)TOTAL_E * 4);
  int* rowptr  = (int*)alloc((size_t)(NL_NN + 32) * 4);
  float* wsumg = (float*)alloc((size_t)NL_NN * 4);
  float* epf   = (float*)alloc((size_t)TOTAL_SLOTS * 32 + 256);  // recs + pad
  unsigned short* out_pre = (unsigned short*)alloc((size_t)NL_NN * 32 * 2);
  float* gsum   = (float*)alloc(N_LAYERS * 32 * 4);
  float* gsumsq = (float*)alloc(N_LAYERS * 32 * 4);
  float* xpad   = (float*)alloc((size_t)N_NODES * 8 * 4);
  __hip_bfloat16* w1t = (__hip_bfloat16*)alloc((size_t)896 * 800 * 2);
  float* pbuf = (float*)alloc((size_t)NPAD * NGRP * 5 * 4);  // 5.6 MB partials
  unsigned short* hn = (unsigned short*)alloc((size_t)N_LAYERS * NPAD * 32 * 2);

  prep_kernel<<<PREP_BLKS, 1024, 0, stream>>>(ei, ew, x, W1, cnt, rank, wsumg,
                                              xpad, w1t, hn);
  scan_a<<<SCAN_BLKS, 1024, 0, stream>>>(cnt, scn, btot, gsum, gsumsq);
  scan_b<<<1, 512, 0, stream>>>(btot, boff);
  fill_kernel<<<FILL_BLKS, 1024, 0, stream>>>(ei, ew, scn, boff, rank, wsumg,
                                              xpad, rowptr, epf);
  attn_kernel<<<ATTN_BLKS, 256, 0, stream>>>(
      xpad, rowptr, epf, Wl, bl, Wr, br, We, att, cb, out_pre, gsum, gsumsq);
  norm_kernel<<<(NL_NN * 8) / 256, 256, 0, stream>>>(
      out_pre, gsum, gsumsq, gam, bet, hn);
  gemm1_kernel<<<G1_BLKS, 256, 0, stream>>>(
      (const short*)hn, (const short*)w1t, b1, W2, pbuf);
  gemm2r_kernel<<<(N_NODES * 5 + 255) / 256, 256, 0, stream>>>(
      pbuf, b2, (float*)d_out);
}

// Round 8
// 453.577 us; speedup vs baseline: 1.3277x; 1.0677x over previous
//
#include <hip/hip_runtime.h>
#include <hip/hip_bf16.h>

#define N_NODES 20000
#define N_EDGES 100000
#define N_LAYERS 25
#define NPAD 20096   // 157*128
#define EPS_BN 1e-5f
#define LOG2E 1.44269504088896340736f
#define NL_NN (N_LAYERS * N_NODES)          // 500000
#define TOTAL_E (N_LAYERS * N_EDGES)        // 2500000
#define TOTAL_SLOTS (TOTAL_E + NL_NN)       // 3000000 (cnt+1 slots per node)
#define SCAN_BLKS ((NL_NN + 1023) / 1024)   // 489
#define QUARTER_N 5000
#define CNT_BLKS (N_LAYERS * 4)             // 100
#define W1T_END (CNT_BLKS + 700)            // 800
#define XPAD_END (W1T_END + 157)            // 957
#define HPAD_BLKS 75                        // 25*96*32 shorts / 1024
#define PREP_BLKS (XPAD_END + HPAD_BLKS)    // 1032
#define EDGE_BLKS ((TOTAL_E + 1023) / 1024) // 2442
#define FILL_BLKS (EDGE_BLKS + SCAN_BLKS)
#define NGRP 14                             // 7 col-tiles x 2 wc halves
#define NPW 8                               // nodes per wave
#define NPL (N_NODES / NPW)                 // 2500 waves per layer
#define ATTN_WAVES (NL_NN / NPW)            // 62500
#define ATTN_BLKS (ATTN_WAVES / 4)          // 15625
#define G1_BLKS (7 * 157)                   // 1099

typedef short short8 __attribute__((ext_vector_type(8)));
typedef short short4v __attribute__((ext_vector_type(4)));
typedef float floatx4 __attribute__((ext_vector_type(4)));
typedef int int8v __attribute__((ext_vector_type(8)));
typedef int int2v __attribute__((ext_vector_type(2)));
typedef int int4v __attribute__((ext_vector_type(4)));

template <int PAT>
__device__ __forceinline__ float swz(float v) {
  return __int_as_float(__builtin_amdgcn_ds_swizzle(__float_as_int(v), PAT));
}

template <int CTRL>
__device__ __forceinline__ float dpp_add(float v) {
  int r = __builtin_amdgcn_update_dpp(0, __float_as_int(v), CTRL, 0xF, 0xF, true);
  return v + __int_as_float(r);
}

// xor16 group-sum via VALU permlane16_swap (no LDS pipe); A=B=p makes the
// half-swap direction irrelevant: r0+r1 = sum of the two 16-lane halves of
// each 32-lane group, broadcast to all lanes. Fallback: ds_swizzle path.
__device__ __forceinline__ float xadd16(float p) {
#if __has_builtin(__builtin_amdgcn_permlane16_swap)
  int2v r = __builtin_amdgcn_permlane16_swap(__float_as_int(p),
                                             __float_as_int(p), false, false);
  return __int_as_float(r[0]) + __int_as_float(r[1]);
#else
  return p + swz<0x401F>(p);
#endif
}

// int index on purpose: 32-bit address math
__device__ __forceinline__ float ldbf(const unsigned short* __restrict__ p, int idx) {
  return __uint_as_float((unsigned)p[idx] << 16);
}

__device__ __forceinline__ unsigned short bfbits(float v) {
  return __builtin_bit_cast(unsigned short, (__hip_bfloat16)v);
}

// async global->LDS, 16B per lane; LDS dest = wave-uniform base + lane*16
__device__ __forceinline__ void gl_lds16(const short* g, short* l) {
  __builtin_amdgcn_global_load_lds(
      (const __attribute__((address_space(1))) void*)g,
      (__attribute__((address_space(3))) void*)l, 16, 0, 0);
}

// scalar load of one 32B row + wait (single asm: wait inseparable)
__device__ __forceinline__ int8v sload8(const void* p) {
  int8v r;
  asm volatile(
      "s_load_dwordx8 %0, %1, 0x0\n\t"
      "s_waitcnt lgkmcnt(0)"
      : "=s"(r)
      : "s"(p));
  return r;
}

// scalar load of 16 ints (two dwordx8, 32B-aligned) + wait
__device__ __forceinline__ void sload_rp(const void* p, int8v& a, int8v& b) {
  asm volatile(
      "s_load_dwordx8 %0, %2, 0x0\n\t"
      "s_load_dwordx8 %1, %2, 0x20\n\t"
      "s_waitcnt lgkmcnt(0)"
      : "=s"(a), "=s"(b)
      : "s"(p));
}

// scalar load of an 8-record chunk (128B, 16B-aligned; SMEM needs only 4B
// alignment) in one block; single wait
__device__ __forceinline__ void sload_chunk(const void* p, int8v& r0, int8v& r1,
                                            int8v& r2, int8v& r3) {
  asm volatile(
      "s_load_dwordx8 %0, %4, 0x0\n\t"
      "s_load_dwordx8 %1, %4, 0x20\n\t"
      "s_load_dwordx8 %2, %4, 0x40\n\t"
      "s_load_dwordx8 %3, %4, 0x60\n\t"
      "s_waitcnt lgkmcnt(0)"
      : "=s"(r0), "=s"(r1), "=s"(r2), "=s"(r3)
      : "s"(p));
}

// 8-chain interleaved 16-lane reduce: single-instruction DPP adds.
// 8-way interleave gives 7-instr gaps (>=2 wait states VALU->DPP);
// s_nop 1 guards asm entry/exit adjacency.
__device__ __forceinline__ void red8(float& p0, float& p1, float& p2, float& p3,
                                     float& p4, float& p5, float& p6, float& p7) {
  asm volatile(
      "s_nop 1\n\t"
      "v_add_f32_dpp %0, %0, %0 quad_perm:[1,0,3,2] row_mask:0xf bank_mask:0xf\n\t"
      "v_add_f32_dpp %1, %1, %1 quad_perm:[1,0,3,2] row_mask:0xf bank_mask:0xf\n\t"
      "v_add_f32_dpp %2, %2, %2 quad_perm:[1,0,3,2] row_mask:0xf bank_mask:0xf\n\t"
      "v_add_f32_dpp %3, %3, %3 quad_perm:[1,0,3,2] row_mask:0xf bank_mask:0xf\n\t"
      "v_add_f32_dpp %4, %4, %4 quad_perm:[1,0,3,2] row_mask:0xf bank_mask:0xf\n\t"
      "v_add_f32_dpp %5, %5, %5 quad_perm:[1,0,3,2] row_mask:0xf bank_mask:0xf\n\t"
      "v_add_f32_dpp %6, %6, %6 quad_perm:[1,0,3,2] row_mask:0xf bank_mask:0xf\n\t"
      "v_add_f32_dpp %7, %7, %7 quad_perm:[1,0,3,2] row_mask:0xf bank_mask:0xf\n\t"
      "v_add_f32_dpp %0, %0, %0 quad_perm:[2,3,0,1] row_mask:0xf bank_mask:0xf\n\t"
      "v_add_f32_dpp %1, %1, %1 quad_perm:[2,3,0,1] row_mask:0xf bank_mask:0xf\n\t"
      "v_add_f32_dpp %2, %2, %2 quad_perm:[2,3,0,1] row_mask:0xf bank_mask:0xf\n\t"
      "v_add_f32_dpp %3, %3, %3 quad_perm:[2,3,0,1] row_mask:0xf bank_mask:0xf\n\t"
      "v_add_f32_dpp %4, %4, %4 quad_perm:[2,3,0,1] row_mask:0xf bank_mask:0xf\n\t"
      "v_add_f32_dpp %5, %5, %5 quad_perm:[2,3,0,1] row_mask:0xf bank_mask:0xf\n\t"
      "v_add_f32_dpp %6, %6, %6 quad_perm:[2,3,0,1] row_mask:0xf bank_mask:0xf\n\t"
      "v_add_f32_dpp %7, %7, %7 quad_perm:[2,3,0,1] row_mask:0xf bank_mask:0xf\n\t"
      "v_add_f32_dpp %0, %0, %0 row_half_mirror row_mask:0xf bank_mask:0xf\n\t"
      "v_add_f32_dpp %1, %1, %1 row_half_mirror row_mask:0xf bank_mask:0xf\n\t"
      "v_add_f32_dpp %2, %2, %2 row_half_mirror row_mask:0xf bank_mask:0xf\n\t"
      "v_add_f32_dpp %3, %3, %3 row_half_mirror row_mask:0xf bank_mask:0xf\n\t"
      "v_add_f32_dpp %4, %4, %4 row_half_mirror row_mask:0xf bank_mask:0xf\n\t"
      "v_add_f32_dpp %5, %5, %5 row_half_mirror row_mask:0xf bank_mask:0xf\n\t"
      "v_add_f32_dpp %6, %6, %6 row_half_mirror row_mask:0xf bank_mask:0xf\n\t"
      "v_add_f32_dpp %7, %7, %7 row_half_mirror row_mask:0xf bank_mask:0xf\n\t"
      "v_add_f32_dpp %0, %0, %0 row_mirror row_mask:0xf bank_mask:0xf\n\t"
      "v_add_f32_dpp %1, %1, %1 row_mirror row_mask:0xf bank_mask:0xf\n\t"
      "v_add_f32_dpp %2, %2, %2 row_mirror row_mask:0xf bank_mask:0xf\n\t"
      "v_add_f32_dpp %3, %3, %3 row_mirror row_mask:0xf bank_mask:0xf\n\t"
      "v_add_f32_dpp %4, %4, %4 row_mirror row_mask:0xf bank_mask:0xf\n\t"
      "v_add_f32_dpp %5, %5, %5 row_mirror row_mask:0xf bank_mask:0xf\n\t"
      "v_add_f32_dpp %6, %6, %6 row_mirror row_mask:0xf bank_mask:0xf\n\t"
      "v_add_f32_dpp %7, %7, %7 row_mirror row_mask:0xf bank_mask:0xf\n\t"
      "s_nop 1"
      : "+v"(p0), "+v"(p1), "+v"(p2), "+v"(p3),
        "+v"(p4), "+v"(p5), "+v"(p6), "+v"(p7));
}

// --- prep: count hist (rank + wsum capture) + W1^T + xpad + hn pad zero -----
__global__ __launch_bounds__(1024) void prep_kernel(
    const int* __restrict__ ei, const float* __restrict__ ew,
    const float* __restrict__ x, const float* __restrict__ W1,
    int* __restrict__ cnt, int* __restrict__ rank,
    float* __restrict__ wsumg, float* __restrict__ xpad,
    __hip_bfloat16* __restrict__ W1bT, unsigned short* __restrict__ hn) {
  __shared__ int smem[QUARTER_N];    // count hist; W1T reuses as float tile
  __shared__ float fsm[QUARTER_N];   // weight sums
  int b = blockIdx.x;
  if (b < CNT_BLKS) {
    int l = b >> 2, base = (b & 3) * QUARTER_N;
    for (int i = threadIdx.x; i < QUARTER_N; i += 1024) {
      smem[i] = 0;
      fsm[i] = 0.f;
    }
    __syncthreads();
    const int* dstp = ei + (size_t)l * 2 * N_EDGES + N_EDGES;
    const float* ewp = ew + (size_t)l * N_EDGES;
    int* rkp = rank + l * N_EDGES;
    for (int e = threadIdx.x; e < N_EDGES; e += 1024) {
      int d = dstp[e] - base;
      if ((unsigned)d < (unsigned)QUARTER_N) {
        rkp[e] = atomicAdd(&smem[d], 1);
        atomicAdd(&fsm[d], ewp[e]);
      }
    }
    __syncthreads();
    int* outp = cnt + l * N_NODES + base;
    float* wp = wsumg + l * N_NODES + base;
    for (int i = threadIdx.x; i < QUARTER_N; i += 1024) {
      outp[i] = smem[i];
      wp[i] = fsm[i];
    }
  } else if (b < W1T_END) {
    float* tile = (float*)smem;  // [32][33]
    int bb = b - CNT_BLKS;
    int j0 = (bb % 28) * 32, k0 = (bb / 28) * 32;
    int tx = threadIdx.x & 31, ty = threadIdx.x >> 5;
    tile[ty * 33 + tx] = (j0 + tx < 800) ? W1[(k0 + ty) * 800 + j0 + tx] : 0.f;
    __syncthreads();
    W1bT[(size_t)(j0 + ty) * 800 + k0 + tx] = (__hip_bfloat16)tile[tx * 33 + ty];
  } else if (b < XPAD_END) {
    int idx = (b - W1T_END) * 1024 + threadIdx.x;
    if (idx < N_NODES * 8) {
      int nn = idx >> 3, k = idx & 7;
      xpad[idx] = (k < 5) ? x[nn * 5 + k] : 0.f;
    }
  } else {
    // zero hn pad rows (N_NODES..NPAD) so gemm1 reads finite values
    int idx = (b - XPAD_END) * 1024 + threadIdx.x;
    const int per_l = (NPAD - N_NODES) * 32;  // 3072
    if (idx < N_LAYERS * per_l) {
      int l = idx / per_l;
      int rem = idx - l * per_l;
      hn[((size_t)l * NPAD + N_NODES) * 32 + rem] = 0;
    }
  }
}

// -------- scan_a: per-block scan over (cnt+1) slots; zero gsum/gsumsq -------
__global__ __launch_bounds__(1024) void scan_a(const int* __restrict__ cnt,
                                               int* __restrict__ scn,
                                               int* __restrict__ btot,
                                               float* __restrict__ gsum,
                                               float* __restrict__ gsumsq) {
  int t = threadIdx.x, b = blockIdx.x;
  int i = b * 1024 + t;
  int lane = t & 63, wv = t >> 6;
  int v = (i < NL_NN) ? cnt[i] + 1 : 0;  // +1: inline self-loop slot
  int sc = v;
#pragma unroll
  for (int off = 1; off < 64; off <<= 1) {
    int u = __shfl_up(sc, off);
    if (lane >= off) sc += u;
  }
  __shared__ int ws[16];
  if (lane == 63) ws[wv] = sc;
  __syncthreads();
  if (t < 16) {
    int xx = ws[t];
#pragma unroll
    for (int off = 1; off < 16; off <<= 1) {
      int u = __shfl_up(xx, off);
      if (t >= off) xx += u;
    }
    ws[t] = xx;
  }
  __syncthreads();
  int bofs = wv ? ws[wv - 1] : 0;
  if (i < NL_NN) scn[i] = bofs + sc - v;
  if (t == 0) btot[b] = ws[15];
  if (b == 200 && t < N_LAYERS * 32) {
    gsum[t] = 0.f;
    gsumsq[t] = 0.f;
  }
}

__global__ __launch_bounds__(512) void scan_b(const int* __restrict__ btot,
                                              int* __restrict__ boff) {
  int t = threadIdx.x;
  int lane = t & 63, wv = t >> 6;
  int v = (t < SCAN_BLKS) ? btot[t] : 0;
  int sc = v;
#pragma unroll
  for (int off = 1; off < 64; off <<= 1) {
    int u = __shfl_up(sc, off);
    if (lane >= off) sc += u;
  }
  __shared__ int ws[8];
  if (lane == 63) ws[wv] = sc;
  __syncthreads();
  if (t < 8) {
    int xx = ws[t];
#pragma unroll
    for (int off = 1; off < 8; off <<= 1) {
      int u = __shfl_up(xx, off);
      if (t >= off) xx += u;
    }
    ws[t] = xx;
  }
  __syncthreads();
  int bofs = wv ? ws[wv - 1] : 0;
  if (t < SCAN_BLKS) boff[t] = bofs + sc - v;
}

// ------- fill: edge-parallel; 16B records {w:f32, x0..x4 bf16-packed} -------
// tail: builds rowptr AND appends the self-loop record per node at slot cnt
// (w = mean incoming weight, x = own node's x) so attn has no self tail.
__global__ __launch_bounds__(1024) void fill_kernel(const int* __restrict__ ei,
                                                    const float* __restrict__ ew,
                                                    const int* __restrict__ scn,
                                                    const int* __restrict__ boff,
                                                    const int* __restrict__ rank,
                                                    const float* __restrict__ wsumg,
                                                    const float* __restrict__ xpad,
                                                    int* __restrict__ rowptr,
                                                    int* __restrict__ epr) {
  int b = blockIdx.x;
  if (b < EDGE_BLKS) {
    int idx = b * 1024 + threadIdx.x;
    if (idx >= TOTAL_E) return;
    int l = idx / N_EDGES, e = idx - l * N_EDGES;
    int src = ei[(size_t)l * 2 * N_EDGES + e];
    int dst = ei[(size_t)l * 2 * N_EDGES + N_EDGES + e];
    int g = l * N_NODES + dst;
    int pos = scn[g] + boff[g >> 10] + rank[idx];
    float w = ew[(size_t)l * N_EDGES + e];
    float4 xv = *(const float4*)(xpad + (size_t)src * 8);
    float x4v = xpad[(size_t)src * 8 + 4];
    int4v r;
    r[0] = __float_as_int(w);
    r[1] = (int)bfbits(xv.x) | ((int)bfbits(xv.y) << 16);
    r[2] = (int)bfbits(xv.z) | ((int)bfbits(xv.w) << 16);
    r[3] = (int)bfbits(x4v);
    *(int4v*)(epr + (size_t)pos * 4) = r;
  } else {
    int i = (b - EDGE_BLKS) * 1024 + threadIdx.x;
    if (i < NL_NN) {
      int st = scn[i] + boff[i >> 10];
      int en = (i + 1 < NL_NN) ? scn[i + 1] + boff[(i + 1) >> 10] : TOTAL_SLOTS;
      rowptr[i] = st;
      int cw = en - st - 1;  // real incoming-edge count
      float wm = wsumg[i] * __builtin_amdgcn_rcpf(fmaxf((float)cw, 1.f));
      int n = i - (i / N_NODES) * N_NODES;
      float4 xv = *(const float4*)(xpad + (size_t)n * 8);
      float x4v = xpad[(size_t)n * 8 + 4];
      int4v r;
      r[0] = __float_as_int(wm);
      r[1] = (int)bfbits(xv.x) | ((int)bfbits(xv.y) << 16);
      r[2] = (int)bfbits(xv.z) | ((int)bfbits(xv.w) << 16);
      r[3] = (int)bfbits(x4v);
      *(int4v*)(epr + (size_t)(en - 1) * 4) = r;  // self record at slot cnt
    }
    if (i < 31) rowptr[NL_NN + i] = TOTAL_SLOTS;  // sentinel + OOB-read pad
    if (i < 8) {
      int4v z = {0, 0, 0, 0};
      *(int4v*)(epr + (size_t)(TOTAL_SLOTS + i) * 4) = z;
    }
  }
}

// ---------------- fused GAT layer: 1 wave per 8 (layer,node)s ----------------
// 16B records: one 128B sload_chunk covers 8 edges (half the SMEM requests).
// bf16 x unpack = scalar ALU (parallel pipe). Self-loop rides the stream.
// BatchNorm partials block-reduced in LDS: 1 atomic set per block (4x fewer).
__global__ __launch_bounds__(256) void attn_kernel(
    const float* __restrict__ xpad, const int* __restrict__ rowptr,
    const int* __restrict__ epr,
    const float* __restrict__ Wl, const float* __restrict__ bl,
    const float* __restrict__ Wr, const float* __restrict__ br,
    const float* __restrict__ We, const float* __restrict__ att,
    const float* __restrict__ cbias, unsigned short* __restrict__ out_pre,
    float* __restrict__ gsum, float* __restrict__ gsumsq) {
  __shared__ float sb[256];
  int b = blockIdx.x;
  // m204 bijective XCD swizzle (ATTN_BLKS % 8 != 0)
  const int q = ATTN_BLKS >> 3, r = ATTN_BLKS & 7;
  int xcd = b & 7, ib = b >> 3;
  int nb = (xcd < r ? xcd * (q + 1) : r * (q + 1) + (xcd - r) * q) + ib;
  int tid = threadIdx.x;
  int w = tid >> 6;
  // wave-uniform by construction; readfirstlane makes it SGPR for the compiler
  int wid = __builtin_amdgcn_readfirstlane(nb * 4 + w);
  int lane = tid & 63;
  int l = wid / NPL;
  int n0 = (wid - l * NPL) * NPW;

  // layer params, once per wave (L1/L2-hot)
  float wlv0 = Wl[(l * 5 + 0) * 64 + lane];
  float wlv1 = Wl[(l * 5 + 1) * 64 + lane];
  float wlv2 = Wl[(l * 5 + 2) * 64 + lane];
  float wlv3 = Wl[(l * 5 + 3) * 64 + lane];
  float wlv4 = Wl[(l * 5 + 4) * 64 + lane];
  float wr0 = Wr[(l * 5 + 0) * 64 + lane];
  float wr1 = Wr[(l * 5 + 1) * 64 + lane];
  float wr2 = Wr[(l * 5 + 2) * 64 + lane];
  float wr3 = Wr[(l * 5 + 3) * 64 + lane];
  float wr4 = Wr[(l * 5 + 4) * 64 + lane];
  float blv = bl[l * 64 + lane];
  float brv = br[l * 64 + lane];
  float wev = We[l * 64 + lane];
  float att2v = att[l * 64 + lane] * LOG2E;
  float cbv = cbias[l * 32 + (lane & 31)];

  // 9 CSR slot offsets for this wave's 8 nodes
  int8v rpa, rpb;
  sload_rp(rowptr + (size_t)wid * 8, rpa, rpb);

  float s1 = 0.f, s2 = 0.f;  // BatchNorm partials

#pragma unroll
  for (int i = 0; i < NPW; i++) {
    int st = rpa[i & 7];
    int en = (i == 7) ? rpb[0] : rpa[(i + 1) & 7];
    int valid = en - st;  // cnt+1 (self-loop inline), >= 1

    // dst transform from scalar x row (source transforms come from records)
    int8v xn = sload8(xpad + (size_t)(n0 + i) * 8);
    float xrn = brv;
    xrn = fmaf(__int_as_float(xn[0]), wr0, xrn);
    xrn = fmaf(__int_as_float(xn[1]), wr1, xrn);
    xrn = fmaf(__int_as_float(xn[2]), wr2, xrn);
    xrn = fmaf(__int_as_float(xn[3]), wr3, xrn);
    xrn = fmaf(__int_as_float(xn[4]), wr4, xrn);

    float ssum = 0.f, acc = 0.f;
    int nchunk = (valid + 7) >> 3;
    for (int c = 0; c < nchunk; c++) {
      int8v r0, r1, r2, r3;
      sload_chunk((const char*)epr + (size_t)(st + c * 8) * 16, r0, r1, r2, r3);
      int m = valid - c * 8;  // valid records this chunk
      float xa[8], pk[8];
#define RVEC(k) ((k) < 2 ? r0 : (k) < 4 ? r1 : (k) < 6 ? r2 : r3)
#define RD(k, j) (RVEC(k)[((k)&1) * 4 + (j)])
#pragma unroll
      for (int k = 0; k < 8; k++) {
        float wgt = __int_as_float(RD(k, 0));
        int d1 = RD(k, 1), d2 = RD(k, 2), d3 = RD(k, 3);
        // bf16 unpack on the scalar pipe (values are wave-uniform)
        float x0 = __int_as_float(d1 << 16);
        float x1 = __int_as_float(d1 & (int)0xffff0000);
        float x2 = __int_as_float(d2 << 16);
        float x3 = __int_as_float(d2 & (int)0xffff0000);
        float x4 = __int_as_float(d3 << 16);
        float a = fmaf(x0, wlv0, blv);
        a = fmaf(x1, wlv1, a);
        a = fmaf(x2, wlv2, a);
        a = fmaf(x3, wlv3, a);
        a = fmaf(x4, wlv4, a);
        xa[k] = a;
        float v = a + fmaf(wgt, wev, xrn);
        float lk = fmaxf(v, 0.2f * v);
        pk[k] = lk * att2v;
      }
#undef RVEC
#undef RD
      red8(pk[0], pk[1], pk[2], pk[3], pk[4], pk[5], pk[6], pk[7]);
#pragma unroll
      for (int k = 0; k < 8; k++) pk[k] = xadd16(pk[k]);
#pragma unroll
      for (int k = 0; k < 8; k++) {
        float pe = __builtin_amdgcn_exp2f(pk[k]);
        pe = (k < m) ? pe : 0.f;  // pad-slot mask (garbage-safe post-exp)
        ssum += pe;
        acc = fmaf(xa[k], pe, acc);
      }
    }
    float outv = acc * __builtin_amdgcn_rcpf(ssum * (float)valid);
    float o2 = outv + __shfl_xor(outv, 32);
    float oval = 0.5f * o2 + cbv;  // symmetric across lane^32
    if (lane < 32)
      out_pre[((size_t)wid * NPW + i) * 32 + lane] = bfbits(oval);
    s1 += oval;
    s2 = fmaf(oval, oval, s2);
  }
  // block-level stats reduce: all 4 waves share one layer (NPL % 4 == 0)
  sb[tid] = (lane < 32) ? s1 : s2;  // lanes 32-63 hold s2 (oval symmetric)
  __syncthreads();
  if (tid < 64) {
    float t = sb[tid] + sb[tid + 64] + sb[tid + 128] + sb[tid + 192];
    if (tid < 32)
      atomicAdd(&gsum[l * 32 + tid], t);
    else
      atomicAdd(&gsumsq[l * 32 + tid - 32], t);
  }
}

// ------- normalize + leaky relu -> bf16 [L][NPAD][32] -----------------------
__global__ __launch_bounds__(256) void norm_kernel(const unsigned short* __restrict__ out_pre,
                                                   const float* __restrict__ gsum,
                                                   const float* __restrict__ gsumsq,
                                                   const float* __restrict__ gamma,
                                                   const float* __restrict__ beta,
                                                   unsigned short* __restrict__ hn) {
  int idx = blockIdx.x * 256 + threadIdx.x;
  int l = idx / (N_NODES * 8);
  int rem = idx - l * (N_NODES * 8);
  int n = rem >> 3, q = rem & 7;
  int c0 = q * 4;
  short4v v4 = *(const short4v*)(out_pre + (l * N_NODES + n) * 32 + c0);
  short4v o;
#pragma unroll
  for (int i = 0; i < 4; i++) {
    int c = c0 + i;
    float mu = gsum[l * 32 + c] * (1.f / N_NODES);
    float var = gsumsq[l * 32 + c] * (1.f / N_NODES) - mu * mu;
    float vv = __uint_as_float((unsigned)(unsigned short)v4[i] << 16);
    float v = gamma[l * 32 + c] * (vv - mu) * rsqrtf(var + EPS_BN) + beta[l * 32 + c];
    v = v > 0.f ? v : 0.01f * v;
    o[i] = (short)bfbits(v);
  }
  *(short4v*)(hn + ((size_t)l * NPAD + n) * 32 + c0) = o;
}

// --- GEMM1: h @ W1 -> relu -> per-colgroup 5-dot partials (non-atomic) ------
// 1D grid + bijective XCD swizzle: each XCD owns a contiguous row-tile range,
// so its ~4MB hn slice stays L2-resident across the 7 column passes.
__global__ __launch_bounds__(256) void gemm1_kernel(const short* __restrict__ hn,
                                                    const short* __restrict__ W1bT,
                                                    const float* __restrict__ b1,
                                                    const float* __restrict__ W2,
                                                    float* __restrict__ p) {
  __shared__ __align__(16) short As[128 * 32];
  __shared__ __align__(16) short Bs[128 * 32];
  const int q = G1_BLKS >> 3, r = G1_BLKS & 7;  // 137, 3
  int bf = blockIdx.x;
  int xcd = bf & 7, ib = bf >> 3;
  int nb = (xcd < r ? xcd * (q + 1) : r * (q + 1) + (xcd - r) * q) + ib;
  int mt = nb / 7, nt = nb - mt * 7;
  int n0 = nt * 128, m0 = mt * 128;
  int t = threadIdx.x;
  int wave = t >> 6, lane = t & 63;
  int wr = wave >> 1, wc = wave & 1;
  int mrow = lane & 15, quad = lane >> 4;
  floatx4 acc[4][4];
#pragma unroll
  for (int i = 0; i < 4; i++)
#pragma unroll
    for (int j = 0; j < 4; j++) acc[i][j] = (floatx4){0.f, 0.f, 0.f, 0.f};

  int r0 = t >> 2, s0 = t & 3;
  int r1 = (t + 256) >> 2, s1 = (t + 256) & 3;
  const short* aG0 = hn + (m0 + r0) * 32 + s0 * 8;
  const short* aG1 = hn + (m0 + r1) * 32 + s1 * 8;
  const short* bG0 = W1bT + (n0 + r0) * 800 + s0 * 8;
  const short* bG1 = W1bT + (n0 + r1) * 800 + s1 * 8;
  const int ak = NPAD * 32;
  short* aD0 = As + wave * 512;
  short* aD1 = As + 2048 + wave * 512;
  short* bD0 = Bs + wave * 512;
  short* bD1 = Bs + 2048 + wave * 512;

  for (int kt = 0; kt < 25; kt++) {
    gl_lds16(aG0, aD0);
    gl_lds16(aG1, aD1);
    gl_lds16(bG0, bD0);
    gl_lds16(bG1, bD1);
    aG0 += ak; aG1 += ak; bG0 += 32; bG1 += 32;
    __syncthreads();
    short8 af[4], bfr[4];
#pragma unroll
    for (int i = 0; i < 4; i++)
      af[i] = *(const short8*)(&As[(wr * 64 + i * 16 + mrow) * 32 + quad * 8]);
#pragma unroll
    for (int j = 0; j < 4; j++)
      bfr[j] = *(const short8*)(&Bs[(wc * 64 + j * 16 + mrow) * 32 + quad * 8]);
#pragma unroll
    for (int i = 0; i < 4; i++)
#pragma unroll
      for (int j = 0; j < 4; j++)
        acc[i][j] = __builtin_amdgcn_mfma_f32_16x16x32_bf16(af[i], bfr[j], acc[i][j], 0, 0, 0);
    __syncthreads();
  }

  // epilogue: relu+bias, 5-dot with W2, 16-lane DPP reduce, disjoint stores
  float w2v[4][5];
  float b1v[4];
#pragma unroll
  for (int j = 0; j < 4; j++) {
    int col = n0 + wc * 64 + j * 16 + mrow;
    bool ok = col < 800;
    b1v[j] = ok ? b1[col] : 0.f;
#pragma unroll
    for (int jj = 0; jj < 5; jj++) w2v[j][jj] = ok ? W2[col * 5 + jj] : 0.f;
  }
  int grp = nt * 2 + wc;
#pragma unroll
  for (int i = 0; i < 4; i++) {
#pragma unroll
    for (int rr = 0; rr < 4; rr++) {
      float s[5] = {0.f, 0.f, 0.f, 0.f, 0.f};
#pragma unroll
      for (int j = 0; j < 4; j++) {
        float v = fmaxf(acc[i][j][rr] + b1v[j], 0.f);
#pragma unroll
        for (int jj = 0; jj < 5; jj++) s[jj] = fmaf(v, w2v[j][jj], s[jj]);
      }
#pragma unroll
      for (int jj = 0; jj < 5; jj++) {
        s[jj] = dpp_add<0xB1>(s[jj]);
        s[jj] = dpp_add<0x4E>(s[jj]);
        s[jj] = dpp_add<0x141>(s[jj]);
        s[jj] = dpp_add<0x140>(s[jj]);
      }
      int row = m0 + wr * 64 + i * 16 + quad * 4 + rr;
      if (mrow == 0) {
#pragma unroll
        for (int jj = 0; jj < 5; jj++)
          p[(row * NGRP + grp) * 5 + jj] = s[jj];
      }
    }
  }
}

// ---- gemm2r: out[row][jj] = b2[jj] + sum_g p[row][g][jj] -------------------
__global__ __launch_bounds__(256) void gemm2r_kernel(const float* __restrict__ p,
                                                     const float* __restrict__ b2,
                                                     float* __restrict__ out) {
  int idx = blockIdx.x * 256 + threadIdx.x;
  if (idx >= N_NODES * 5) return;
  int row = idx / 5, jj = idx - row * 5;
  float s = b2[jj];
#pragma unroll
  for (int g = 0; g < NGRP; g++) s += p[(row * NGRP + g) * 5 + jj];
  out[idx] = s;
}

extern "C" void kernel_launch(void* const* d_in, const int* in_sizes, int n_in,
                              void* d_out, int out_size, void* d_ws, size_t ws_size,
                              hipStream_t stream) {
  const float* x    = (const float*)d_in[0];
  const int*   ei   = (const int*)d_in[1];
  const float* ew   = (const float*)d_in[2];
  const float* Wl   = (const float*)d_in[3];
  const float* bl   = (const float*)d_in[4];
  const float* Wr   = (const float*)d_in[5];
  const float* br   = (const float*)d_in[6];
  const float* We   = (const float*)d_in[7];
  const float* att  = (const float*)d_in[8];
  const float* cb   = (const float*)d_in[9];
  const float* gam  = (const float*)d_in[10];
  const float* bet  = (const float*)d_in[11];
  const float* W1   = (const float*)d_in[12];
  const float* b1   = (const float*)d_in[13];
  const float* W2   = (const float*)d_in[14];
  const float* b2   = (const float*)d_in[15];

  char* ws = (char*)d_ws;
  size_t off = 0;
  auto alloc = [&](size_t bytes) {
    void* p = ws + off;
    off = (off + bytes + 255) & ~(size_t)255;
    return p;
  };
  int* cnt     = (int*)alloc((size_t)NL_NN * 4);
  int* scn     = (int*)alloc((size_t)NL_NN * 4);
  int* btot    = (int*)alloc(SCAN_BLKS * 4);
  int* boff    = (int*)alloc(SCAN_BLKS * 4);
  int* rank    = (int*)alloc((size_t)TOTAL_E * 4);
  int* rowptr  = (int*)alloc((size_t)(NL_NN + 32) * 4);
  float* wsumg = (float*)alloc((size_t)NL_NN * 4);
  int* epr     = (int*)alloc((size_t)TOTAL_SLOTS * 16 + 256);  // 16B recs + pad
  unsigned short* out_pre = (unsigned short*)alloc((size_t)NL_NN * 32 * 2);
  float* gsum   = (float*)alloc(N_LAYERS * 32 * 4);
  float* gsumsq = (float*)alloc(N_LAYERS * 32 * 4);
  float* xpad   = (float*)alloc((size_t)N_NODES * 8 * 4);
  __hip_bfloat16* w1t = (__hip_bfloat16*)alloc((size_t)896 * 800 * 2);
  float* pbuf = (float*)alloc((size_t)NPAD * NGRP * 5 * 4);  // 5.6 MB partials
  unsigned short* hn = (unsigned short*)alloc((size_t)N_LAYERS * NPAD * 32 * 2);

  prep_kernel<<<PREP_BLKS, 1024, 0, stream>>>(ei, ew, x, W1, cnt, rank, wsumg,
                                              xpad, w1t, hn);
  scan_a<<<SCAN_BLKS, 1024, 0, stream>>>(cnt, scn, btot, gsum, gsumsq);
  scan_b<<<1, 512, 0, stream>>>(btot, boff);
  fill_kernel<<<FILL_BLKS, 1024, 0, stream>>>(ei, ew, scn, boff, rank, wsumg,
                                              xpad, rowptr, epr);
  attn_kernel<<<ATTN_BLKS, 256, 0, stream>>>(
      xpad, rowptr, epr, Wl, bl, Wr, br, We, att, cb, out_pre, gsum, gsumsq);
  norm_kernel<<<(NL_NN * 8) / 256, 256, 0, stream>>>(
      out_pre, gsum, gsumsq, gam, bet, hn);
  gemm1_kernel<<<G1_BLKS, 256, 0, stream>>>(
      (const short*)hn, (const short*)w1t, b1, W2, pbuf);
  gemm2r_kernel<<<(N_NODES * 5 + 255) / 256, 256, 0, stream>>>(
      pbuf, b2, (float*)d_out);
}

// Round 9
// 441.975 us; speedup vs baseline: 1.3625x; 1.0263x over previous
//
#include <hip/hip_runtime.h>
#include <hip/hip_bf16.h>

#define N_NODES 20000
#define N_EDGES 100000
#define N_LAYERS 25
#define NPAD 20096   // 157*128
#define EPS_BN 1e-5f
#define LOG2E 1.44269504088896340736f
#define NL_NN (N_LAYERS * N_NODES)          // 500000
#define TOTAL_E (N_LAYERS * N_EDGES)        // 2500000
#define TOTAL_SLOTS (TOTAL_E + NL_NN)       // 3000000 (cnt+1 slots per node)
#define SCAN_BLKS ((NL_NN + 1023) / 1024)   // 489
#define QUARTER_N 5000
#define CNT_BLKS (N_LAYERS * 4)             // 100
#define W1T_END (CNT_BLKS + 700)            // 800
#define XPAD_END (W1T_END + 157)            // 957
#define HPAD_BLKS 75                        // 25*96*32 shorts / 1024
#define PREP_BLKS (XPAD_END + HPAD_BLKS)    // 1032
#define EDGE_BLKS ((TOTAL_E + 1023) / 1024) // 2442
#define FILL_BLKS (EDGE_BLKS + SCAN_BLKS)
#define NGRP 14                             // 7 col-tiles x 2 wc halves
#define NPW 8                               // nodes per wave
#define NPL (N_NODES / NPW)                 // 2500 waves per layer
#define ATTN_WAVES (NL_NN / NPW)            // 62500
#define ATTN_BLKS (ATTN_WAVES / 4)          // 15625
#define G1_BLKS (7 * 157)                   // 1099

typedef short short8 __attribute__((ext_vector_type(8)));
typedef short short4v __attribute__((ext_vector_type(4)));
typedef float floatx4 __attribute__((ext_vector_type(4)));
typedef int int8v __attribute__((ext_vector_type(8)));
typedef int int2v __attribute__((ext_vector_type(2)));
typedef int int4v __attribute__((ext_vector_type(4)));

template <int PAT>
__device__ __forceinline__ float swz(float v) {
  return __int_as_float(__builtin_amdgcn_ds_swizzle(__float_as_int(v), PAT));
}

template <int CTRL>
__device__ __forceinline__ float dpp_add(float v) {
  int r = __builtin_amdgcn_update_dpp(0, __float_as_int(v), CTRL, 0xF, 0xF, true);
  return v + __int_as_float(r);
}

// xor16 group-sum via VALU permlane16_swap (no LDS pipe); A=B=p makes the
// half-swap direction irrelevant: r0+r1 = sum of the two 16-lane halves of
// each 32-lane group, broadcast to all lanes. Fallback: ds_swizzle path.
__device__ __forceinline__ float xadd16(float p) {
#if __has_builtin(__builtin_amdgcn_permlane16_swap)
  int2v r = __builtin_amdgcn_permlane16_swap(__float_as_int(p),
                                             __float_as_int(p), false, false);
  return __int_as_float(r[0]) + __int_as_float(r[1]);
#else
  return p + swz<0x401F>(p);
#endif
}

// int index on purpose: 32-bit address math
__device__ __forceinline__ float ldbf(const unsigned short* __restrict__ p, int idx) {
  return __uint_as_float((unsigned)p[idx] << 16);
}

__device__ __forceinline__ unsigned short bfbits(float v) {
  return __builtin_bit_cast(unsigned short, (__hip_bfloat16)v);
}

// async global->LDS, 16B per lane; LDS dest = wave-uniform base + lane*16
__device__ __forceinline__ void gl_lds16(const short* g, short* l) {
  __builtin_amdgcn_global_load_lds(
      (const __attribute__((address_space(1))) void*)g,
      (__attribute__((address_space(3))) void*)l, 16, 0, 0);
}

// scalar load of one 32B row + wait (single asm: wait inseparable)
__device__ __forceinline__ int8v sload8(const void* p) {
  int8v r;
  asm volatile(
      "s_load_dwordx8 %0, %1, 0x0\n\t"
      "s_waitcnt lgkmcnt(0)"
      : "=s"(r)
      : "s"(p));
  return r;
}

// scalar load of 16 ints (two dwordx8) + wait; used for rowptr AND 4-record
// (64B) edge chunks over 16B records
__device__ __forceinline__ void sload_rp(const void* p, int8v& a, int8v& b) {
  asm volatile(
      "s_load_dwordx8 %0, %2, 0x0\n\t"
      "s_load_dwordx8 %1, %2, 0x20\n\t"
      "s_waitcnt lgkmcnt(0)"
      : "=s"(a), "=s"(b)
      : "s"(p));
}

// 4-chain interleaved 16-lane reduce: single-instruction DPP adds.
// 4-way interleave gives 3-instr gaps (>=2 wait states VALU->DPP);
// s_nop 1 guards asm entry/exit adjacency.
__device__ __forceinline__ void red4(float& p0, float& p1, float& p2, float& p3) {
  asm volatile(
      "s_nop 1\n\t"
      "v_add_f32_dpp %0, %0, %0 quad_perm:[1,0,3,2] row_mask:0xf bank_mask:0xf\n\t"
      "v_add_f32_dpp %1, %1, %1 quad_perm:[1,0,3,2] row_mask:0xf bank_mask:0xf\n\t"
      "v_add_f32_dpp %2, %2, %2 quad_perm:[1,0,3,2] row_mask:0xf bank_mask:0xf\n\t"
      "v_add_f32_dpp %3, %3, %3 quad_perm:[1,0,3,2] row_mask:0xf bank_mask:0xf\n\t"
      "v_add_f32_dpp %0, %0, %0 quad_perm:[2,3,0,1] row_mask:0xf bank_mask:0xf\n\t"
      "v_add_f32_dpp %1, %1, %1 quad_perm:[2,3,0,1] row_mask:0xf bank_mask:0xf\n\t"
      "v_add_f32_dpp %2, %2, %2 quad_perm:[2,3,0,1] row_mask:0xf bank_mask:0xf\n\t"
      "v_add_f32_dpp %3, %3, %3 quad_perm:[2,3,0,1] row_mask:0xf bank_mask:0xf\n\t"
      "v_add_f32_dpp %0, %0, %0 row_half_mirror row_mask:0xf bank_mask:0xf\n\t"
      "v_add_f32_dpp %1, %1, %1 row_half_mirror row_mask:0xf bank_mask:0xf\n\t"
      "v_add_f32_dpp %2, %2, %2 row_half_mirror row_mask:0xf bank_mask:0xf\n\t"
      "v_add_f32_dpp %3, %3, %3 row_half_mirror row_mask:0xf bank_mask:0xf\n\t"
      "v_add_f32_dpp %0, %0, %0 row_mirror row_mask:0xf bank_mask:0xf\n\t"
      "v_add_f32_dpp %1, %1, %1 row_mirror row_mask:0xf bank_mask:0xf\n\t"
      "v_add_f32_dpp %2, %2, %2 row_mirror row_mask:0xf bank_mask:0xf\n\t"
      "v_add_f32_dpp %3, %3, %3 row_mirror row_mask:0xf bank_mask:0xf\n\t"
      "s_nop 1"
      : "+v"(p0), "+v"(p1), "+v"(p2), "+v"(p3));
}

// --- prep: count hist (rank + wsum capture) + W1^T + xpad + hn pad zero -----
__global__ __launch_bounds__(1024) void prep_kernel(
    const int* __restrict__ ei, const float* __restrict__ ew,
    const float* __restrict__ x, const float* __restrict__ W1,
    int* __restrict__ cnt, int* __restrict__ rank,
    float* __restrict__ wsumg, float* __restrict__ xpad,
    __hip_bfloat16* __restrict__ W1bT, unsigned short* __restrict__ hn) {
  __shared__ int smem[QUARTER_N];    // count hist; W1T reuses as float tile
  __shared__ float fsm[QUARTER_N];   // weight sums
  int b = blockIdx.x;
  if (b < CNT_BLKS) {
    int l = b >> 2, base = (b & 3) * QUARTER_N;
    for (int i = threadIdx.x; i < QUARTER_N; i += 1024) {
      smem[i] = 0;
      fsm[i] = 0.f;
    }
    __syncthreads();
    const int* dstp = ei + (size_t)l * 2 * N_EDGES + N_EDGES;
    const float* ewp = ew + (size_t)l * N_EDGES;
    int* rkp = rank + l * N_EDGES;
    for (int e = threadIdx.x; e < N_EDGES; e += 1024) {
      int d = dstp[e] - base;
      if ((unsigned)d < (unsigned)QUARTER_N) {
        rkp[e] = atomicAdd(&smem[d], 1);
        atomicAdd(&fsm[d], ewp[e]);
      }
    }
    __syncthreads();
    int* outp = cnt + l * N_NODES + base;
    float* wp = wsumg + l * N_NODES + base;
    for (int i = threadIdx.x; i < QUARTER_N; i += 1024) {
      outp[i] = smem[i];
      wp[i] = fsm[i];
    }
  } else if (b < W1T_END) {
    float* tile = (float*)smem;  // [32][33]
    int bb = b - CNT_BLKS;
    int j0 = (bb % 28) * 32, k0 = (bb / 28) * 32;
    int tx = threadIdx.x & 31, ty = threadIdx.x >> 5;
    tile[ty * 33 + tx] = (j0 + tx < 800) ? W1[(k0 + ty) * 800 + j0 + tx] : 0.f;
    __syncthreads();
    W1bT[(size_t)(j0 + ty) * 800 + k0 + tx] = (__hip_bfloat16)tile[tx * 33 + ty];
  } else if (b < XPAD_END) {
    int idx = (b - W1T_END) * 1024 + threadIdx.x;
    if (idx < N_NODES * 8) {
      int nn = idx >> 3, k = idx & 7;
      xpad[idx] = (k < 5) ? x[nn * 5 + k] : 0.f;
    }
  } else {
    // zero hn pad rows (N_NODES..NPAD) so gemm1 reads finite values
    int idx = (b - XPAD_END) * 1024 + threadIdx.x;
    const int per_l = (NPAD - N_NODES) * 32;  // 3072
    if (idx < N_LAYERS * per_l) {
      int l = idx / per_l;
      int rem = idx - l * per_l;
      hn[((size_t)l * NPAD + N_NODES) * 32 + rem] = 0;
    }
  }
}

// -------- scan_a: per-block scan over (cnt+1) slots; zero gsum/gsumsq -------
__global__ __launch_bounds__(1024) void scan_a(const int* __restrict__ cnt,
                                               int* __restrict__ scn,
                                               int* __restrict__ btot,
                                               float* __restrict__ gsum,
                                               float* __restrict__ gsumsq) {
  int t = threadIdx.x, b = blockIdx.x;
  int i = b * 1024 + t;
  int lane = t & 63, wv = t >> 6;
  int v = (i < NL_NN) ? cnt[i] + 1 : 0;  // +1: inline self-loop slot
  int sc = v;
#pragma unroll
  for (int off = 1; off < 64; off <<= 1) {
    int u = __shfl_up(sc, off);
    if (lane >= off) sc += u;
  }
  __shared__ int ws[16];
  if (lane == 63) ws[wv] = sc;
  __syncthreads();
  if (t < 16) {
    int xx = ws[t];
#pragma unroll
    for (int off = 1; off < 16; off <<= 1) {
      int u = __shfl_up(xx, off);
      if (t >= off) xx += u;
    }
    ws[t] = xx;
  }
  __syncthreads();
  int bofs = wv ? ws[wv - 1] : 0;
  if (i < NL_NN) scn[i] = bofs + sc - v;
  if (t == 0) btot[b] = ws[15];
  if (b == 200 && t < N_LAYERS * 32) {
    gsum[t] = 0.f;
    gsumsq[t] = 0.f;
  }
}

__global__ __launch_bounds__(512) void scan_b(const int* __restrict__ btot,
                                              int* __restrict__ boff) {
  int t = threadIdx.x;
  int lane = t & 63, wv = t >> 6;
  int v = (t < SCAN_BLKS) ? btot[t] : 0;
  int sc = v;
#pragma unroll
  for (int off = 1; off < 64; off <<= 1) {
    int u = __shfl_up(sc, off);
    if (lane >= off) sc += u;
  }
  __shared__ int ws[8];
  if (lane == 63) ws[wv] = sc;
  __syncthreads();
  if (t < 8) {
    int xx = ws[t];
#pragma unroll
    for (int off = 1; off < 8; off <<= 1) {
      int u = __shfl_up(xx, off);
      if (t >= off) xx += u;
    }
    ws[t] = xx;
  }
  __syncthreads();
  int bofs = wv ? ws[wv - 1] : 0;
  if (t < SCAN_BLKS) boff[t] = bofs + sc - v;
}

// ------- fill: edge-parallel; 16B records {w:f32, x0..x4 bf16-packed} -------
// tail: builds rowptr AND appends the self-loop record per node at slot cnt
// (w = mean incoming weight, x = own node's x) so attn has no self tail.
__global__ __launch_bounds__(1024) void fill_kernel(const int* __restrict__ ei,
                                                    const float* __restrict__ ew,
                                                    const int* __restrict__ scn,
                                                    const int* __restrict__ boff,
                                                    const int* __restrict__ rank,
                                                    const float* __restrict__ wsumg,
                                                    const float* __restrict__ xpad,
                                                    int* __restrict__ rowptr,
                                                    int* __restrict__ epr) {
  int b = blockIdx.x;
  if (b < EDGE_BLKS) {
    int idx = b * 1024 + threadIdx.x;
    if (idx >= TOTAL_E) return;
    int l = idx / N_EDGES, e = idx - l * N_EDGES;
    int src = ei[(size_t)l * 2 * N_EDGES + e];
    int dst = ei[(size_t)l * 2 * N_EDGES + N_EDGES + e];
    int g = l * N_NODES + dst;
    int pos = scn[g] + boff[g >> 10] + rank[idx];
    float w = ew[(size_t)l * N_EDGES + e];
    float4 xv = *(const float4*)(xpad + (size_t)src * 8);
    float x4v = xpad[(size_t)src * 8 + 4];
    int4v r;
    r[0] = __float_as_int(w);
    r[1] = (int)bfbits(xv.x) | ((int)bfbits(xv.y) << 16);
    r[2] = (int)bfbits(xv.z) | ((int)bfbits(xv.w) << 16);
    r[3] = (int)bfbits(x4v);
    *(int4v*)(epr + (size_t)pos * 4) = r;
  } else {
    int i = (b - EDGE_BLKS) * 1024 + threadIdx.x;
    if (i < NL_NN) {
      int st = scn[i] + boff[i >> 10];
      int en = (i + 1 < NL_NN) ? scn[i + 1] + boff[(i + 1) >> 10] : TOTAL_SLOTS;
      rowptr[i] = st;
      int cw = en - st - 1;  // real incoming-edge count
      float wm = wsumg[i] * __builtin_amdgcn_rcpf(fmaxf((float)cw, 1.f));
      int n = i - (i / N_NODES) * N_NODES;
      float4 xv = *(const float4*)(xpad + (size_t)n * 8);
      float x4v = xpad[(size_t)n * 8 + 4];
      int4v r;
      r[0] = __float_as_int(wm);
      r[1] = (int)bfbits(xv.x) | ((int)bfbits(xv.y) << 16);
      r[2] = (int)bfbits(xv.z) | ((int)bfbits(xv.w) << 16);
      r[3] = (int)bfbits(x4v);
      *(int4v*)(epr + (size_t)(en - 1) * 4) = r;  // self record at slot cnt
    }
    if (i < 31) rowptr[NL_NN + i] = TOTAL_SLOTS;  // sentinel + OOB-read pad
    if (i < 8) {
      int4v z = {0, 0, 0, 0};
      *(int4v*)(epr + (size_t)(TOTAL_SLOTS + i) * 4) = z;
    }
  }
}

// ---------------- fused GAT layer: 1 wave per 8 (layer,node)s ----------------
// 16B records, 4-slot chunks (64B dual-dwordx8): minimal padded slot-work
// (4*E[ceil(v/4)] ~ 7.6 slots/node vs 9.2 at 8-wide) on an issue-bound loop.
// bf16 x unpack = scalar ALU (parallel pipe). Self-loop rides the stream.
// BatchNorm partials block-reduced in LDS: 1 atomic set per block.
__global__ __launch_bounds__(256) void attn_kernel(
    const float* __restrict__ xpad, const int* __restrict__ rowptr,
    const int* __restrict__ epr,
    const float* __restrict__ Wl, const float* __restrict__ bl,
    const float* __restrict__ Wr, const float* __restrict__ br,
    const float* __restrict__ We, const float* __restrict__ att,
    const float* __restrict__ cbias, unsigned short* __restrict__ out_pre,
    float* __restrict__ gsum, float* __restrict__ gsumsq) {
  __shared__ float sb[256];
  int b = blockIdx.x;
  // m204 bijective XCD swizzle (ATTN_BLKS % 8 != 0)
  const int q = ATTN_BLKS >> 3, r = ATTN_BLKS & 7;
  int xcd = b & 7, ib = b >> 3;
  int nb = (xcd < r ? xcd * (q + 1) : r * (q + 1) + (xcd - r) * q) + ib;
  int tid = threadIdx.x;
  int w = tid >> 6;
  // wave-uniform by construction; readfirstlane makes it SGPR for the compiler
  int wid = __builtin_amdgcn_readfirstlane(nb * 4 + w);
  int lane = tid & 63;
  int l = wid / NPL;
  int n0 = (wid - l * NPL) * NPW;

  // layer params, once per wave (L1/L2-hot)
  float wlv0 = Wl[(l * 5 + 0) * 64 + lane];
  float wlv1 = Wl[(l * 5 + 1) * 64 + lane];
  float wlv2 = Wl[(l * 5 + 2) * 64 + lane];
  float wlv3 = Wl[(l * 5 + 3) * 64 + lane];
  float wlv4 = Wl[(l * 5 + 4) * 64 + lane];
  float wr0 = Wr[(l * 5 + 0) * 64 + lane];
  float wr1 = Wr[(l * 5 + 1) * 64 + lane];
  float wr2 = Wr[(l * 5 + 2) * 64 + lane];
  float wr3 = Wr[(l * 5 + 3) * 64 + lane];
  float wr4 = Wr[(l * 5 + 4) * 64 + lane];
  float blv = bl[l * 64 + lane];
  float brv = br[l * 64 + lane];
  float wev = We[l * 64 + lane];
  float att2v = att[l * 64 + lane] * LOG2E;
  float cbv = cbias[l * 32 + (lane & 31)];

  // 9 CSR slot offsets for this wave's 8 nodes
  int8v rpa, rpb;
  sload_rp(rowptr + (size_t)wid * 8, rpa, rpb);

  float s1 = 0.f, s2 = 0.f;  // BatchNorm partials

#pragma unroll
  for (int i = 0; i < NPW; i++) {
    int st = rpa[i & 7];
    int en = (i == 7) ? rpb[0] : rpa[(i + 1) & 7];
    int valid = en - st;  // cnt+1 (self-loop inline), >= 1

    // dst transform from scalar x row (source transforms come from records)
    int8v xn = sload8(xpad + (size_t)(n0 + i) * 8);
    float xrn = brv;
    xrn = fmaf(__int_as_float(xn[0]), wr0, xrn);
    xrn = fmaf(__int_as_float(xn[1]), wr1, xrn);
    xrn = fmaf(__int_as_float(xn[2]), wr2, xrn);
    xrn = fmaf(__int_as_float(xn[3]), wr3, xrn);
    xrn = fmaf(__int_as_float(xn[4]), wr4, xrn);

    float ssum = 0.f, acc = 0.f;
    int nchunk = (valid + 3) >> 2;
    for (int c = 0; c < nchunk; c++) {
      int8v r0, r1;
      sload_rp((const char*)epr + (size_t)(st + c * 4) * 16, r0, r1);
      int m = valid - c * 4;  // valid records this chunk
      float xa[4], pk[4];
#define RD(k, j) ((k) < 2 ? r0[(k)*4 + (j)] : r1[((k)-2) * 4 + (j)])
#pragma unroll
      for (int k = 0; k < 4; k++) {
        float wgt = __int_as_float(RD(k, 0));
        int d1 = RD(k, 1), d2 = RD(k, 2), d3 = RD(k, 3);
        // bf16 unpack on the scalar pipe (values are wave-uniform)
        float x0 = __int_as_float(d1 << 16);
        float x1 = __int_as_float(d1 & (int)0xffff0000);
        float x2 = __int_as_float(d2 << 16);
        float x3 = __int_as_float(d2 & (int)0xffff0000);
        float x4 = __int_as_float(d3 << 16);
        float a = fmaf(x0, wlv0, blv);
        a = fmaf(x1, wlv1, a);
        a = fmaf(x2, wlv2, a);
        a = fmaf(x3, wlv3, a);
        a = fmaf(x4, wlv4, a);
        xa[k] = a;
        float v = a + fmaf(wgt, wev, xrn);
        float lk = fmaxf(v, 0.2f * v);
        pk[k] = lk * att2v;
      }
#undef RD
      red4(pk[0], pk[1], pk[2], pk[3]);
#pragma unroll
      for (int k = 0; k < 4; k++) pk[k] = xadd16(pk[k]);
#pragma unroll
      for (int k = 0; k < 4; k++) {
        float pe = __builtin_amdgcn_exp2f(pk[k]);
        pe = (k < m) ? pe : 0.f;  // pad-slot mask (garbage-safe post-exp)
        ssum += pe;
        acc = fmaf(xa[k], pe, acc);
      }
    }
    float outv = acc * __builtin_amdgcn_rcpf(ssum * (float)valid);
    float o2 = outv + __shfl_xor(outv, 32);
    float oval = 0.5f * o2 + cbv;  // symmetric across lane^32
    if (lane < 32)
      out_pre[((size_t)wid * NPW + i) * 32 + lane] = bfbits(oval);
    s1 += oval;
    s2 = fmaf(oval, oval, s2);
  }
  // block-level stats reduce: all 4 waves share one layer (NPL % 4 == 0)
  sb[tid] = (lane < 32) ? s1 : s2;  // lanes 32-63 hold s2 (oval symmetric)
  __syncthreads();
  if (tid < 64) {
    float t = sb[tid] + sb[tid + 64] + sb[tid + 128] + sb[tid + 192];
    if (tid < 32)
      atomicAdd(&gsum[l * 32 + tid], t);
    else
      atomicAdd(&gsumsq[l * 32 + tid - 32], t);
  }
}

// ------- normalize + leaky relu -> bf16 [L][NPAD][32] -----------------------
__global__ __launch_bounds__(256) void norm_kernel(const unsigned short* __restrict__ out_pre,
                                                   const float* __restrict__ gsum,
                                                   const float* __restrict__ gsumsq,
                                                   const float* __restrict__ gamma,
                                                   const float* __restrict__ beta,
                                                   unsigned short* __restrict__ hn) {
  int idx = blockIdx.x * 256 + threadIdx.x;
  int l = idx / (N_NODES * 8);
  int rem = idx - l * (N_NODES * 8);
  int n = rem >> 3, q = rem & 7;
  int c0 = q * 4;
  short4v v4 = *(const short4v*)(out_pre + (l * N_NODES + n) * 32 + c0);
  short4v o;
#pragma unroll
  for (int i = 0; i < 4; i++) {
    int c = c0 + i;
    float mu = gsum[l * 32 + c] * (1.f / N_NODES);
    float var = gsumsq[l * 32 + c] * (1.f / N_NODES) - mu * mu;
    float vv = __uint_as_float((unsigned)(unsigned short)v4[i] << 16);
    float v = gamma[l * 32 + c] * (vv - mu) * rsqrtf(var + EPS_BN) + beta[l * 32 + c];
    v = v > 0.f ? v : 0.01f * v;
    o[i] = (short)bfbits(v);
  }
  *(short4v*)(hn + ((size_t)l * NPAD + n) * 32 + c0) = o;
}

// --- GEMM1: h @ W1 -> relu -> per-colgroup 5-dot partials (non-atomic) ------
// 1D grid + bijective XCD swizzle: each XCD owns a contiguous row-tile range,
// so its ~4MB hn slice stays L2-resident across the 7 column passes.
__global__ __launch_bounds__(256) void gemm1_kernel(const short* __restrict__ hn,
                                                    const short* __restrict__ W1bT,
                                                    const float* __restrict__ b1,
                                                    const float* __restrict__ W2,
                                                    float* __restrict__ p) {
  __shared__ __align__(16) short As[128 * 32];
  __shared__ __align__(16) short Bs[128 * 32];
  const int q = G1_BLKS >> 3, r = G1_BLKS & 7;  // 137, 3
  int bf = blockIdx.x;
  int xcd = bf & 7, ib = bf >> 3;
  int nb = (xcd < r ? xcd * (q + 1) : r * (q + 1) + (xcd - r) * q) + ib;
  int mt = nb / 7, nt = nb - mt * 7;
  int n0 = nt * 128, m0 = mt * 128;
  int t = threadIdx.x;
  int wave = t >> 6, lane = t & 63;
  int wr = wave >> 1, wc = wave & 1;
  int mrow = lane & 15, quad = lane >> 4;
  floatx4 acc[4][4];
#pragma unroll
  for (int i = 0; i < 4; i++)
#pragma unroll
    for (int j = 0; j < 4; j++) acc[i][j] = (floatx4){0.f, 0.f, 0.f, 0.f};

  int r0 = t >> 2, s0 = t & 3;
  int r1 = (t + 256) >> 2, s1 = (t + 256) & 3;
  const short* aG0 = hn + (m0 + r0) * 32 + s0 * 8;
  const short* aG1 = hn + (m0 + r1) * 32 + s1 * 8;
  const short* bG0 = W1bT + (n0 + r0) * 800 + s0 * 8;
  const short* bG1 = W1bT + (n0 + r1) * 800 + s1 * 8;
  const int ak = NPAD * 32;
  short* aD0 = As + wave * 512;
  short* aD1 = As + 2048 + wave * 512;
  short* bD0 = Bs + wave * 512;
  short* bD1 = Bs + 2048 + wave * 512;

  for (int kt = 0; kt < 25; kt++) {
    gl_lds16(aG0, aD0);
    gl_lds16(aG1, aD1);
    gl_lds16(bG0, bD0);
    gl_lds16(bG1, bD1);
    aG0 += ak; aG1 += ak; bG0 += 32; bG1 += 32;
    __syncthreads();
    short8 af[4], bfr[4];
#pragma unroll
    for (int i = 0; i < 4; i++)
      af[i] = *(const short8*)(&As[(wr * 64 + i * 16 + mrow) * 32 + quad * 8]);
#pragma unroll
    for (int j = 0; j < 4; j++)
      bfr[j] = *(const short8*)(&Bs[(wc * 64 + j * 16 + mrow) * 32 + quad * 8]);
#pragma unroll
    for (int i = 0; i < 4; i++)
#pragma unroll
      for (int j = 0; j < 4; j++)
        acc[i][j] = __builtin_amdgcn_mfma_f32_16x16x32_bf16(af[i], bfr[j], acc[i][j], 0, 0, 0);
    __syncthreads();
  }

  // epilogue: relu+bias, 5-dot with W2, 16-lane DPP reduce, disjoint stores
  float w2v[4][5];
  float b1v[4];
#pragma unroll
  for (int j = 0; j < 4; j++) {
    int col = n0 + wc * 64 + j * 16 + mrow;
    bool ok = col < 800;
    b1v[j] = ok ? b1[col] : 0.f;
#pragma unroll
    for (int jj = 0; jj < 5; jj++) w2v[j][jj] = ok ? W2[col * 5 + jj] : 0.f;
  }
  int grp = nt * 2 + wc;
#pragma unroll
  for (int i = 0; i < 4; i++) {
#pragma unroll
    for (int rr = 0; rr < 4; rr++) {
      float s[5] = {0.f, 0.f, 0.f, 0.f, 0.f};
#pragma unroll
      for (int j = 0; j < 4; j++) {
        float v = fmaxf(acc[i][j][rr] + b1v[j], 0.f);
#pragma unroll
        for (int jj = 0; jj < 5; jj++) s[jj] = fmaf(v, w2v[j][jj], s[jj]);
      }
#pragma unroll
      for (int jj = 0; jj < 5; jj++) {
        s[jj] = dpp_add<0xB1>(s[jj]);
        s[jj] = dpp_add<0x4E>(s[jj]);
        s[jj] = dpp_add<0x141>(s[jj]);
        s[jj] = dpp_add<0x140>(s[jj]);
      }
      int row = m0 + wr * 64 + i * 16 + quad * 4 + rr;
      if (mrow == 0) {
#pragma unroll
        for (int jj = 0; jj < 5; jj++)
          p[(row * NGRP + grp) * 5 + jj] = s[jj];
      }
    }
  }
}

// ---- gemm2r: out[row][jj] = b2[jj] + sum_g p[row][g][jj] -------------------
__global__ __launch_bounds__(256) void gemm2r_kernel(const float* __restrict__ p,
                                                     const float* __restrict__ b2,
                                                     float* __restrict__ out) {
  int idx = blockIdx.x * 256 + threadIdx.x;
  if (idx >= N_NODES * 5) return;
  int row = idx / 5, jj = idx - row * 5;
  float s = b2[jj];
#pragma unroll
  for (int g = 0; g < NGRP; g++) s += p[(row * NGRP + g) * 5 + jj];
  out[idx] = s;
}

extern "C" void kernel_launch(void* const* d_in, const int* in_sizes, int n_in,
                              void* d_out, int out_size, void* d_ws, size_t ws_size,
                              hipStream_t stream) {
  const float* x    = (const float*)d_in[0];
  const int*   ei   = (const int*)d_in[1];
  const float* ew   = (const float*)d_in[2];
  const float* Wl   = (const float*)d_in[3];
  const float* bl   = (const float*)d_in[4];
  const float* Wr   = (const float*)d_in[5];
  const float* br   = (const float*)d_in[6];
  const float* We   = (const float*)d_in[7];
  const float* att  = (const float*)d_in[8];
  const float* cb   = (const float*)d_in[9];
  const float* gam  = (const float*)d_in[10];
  const float* bet  = (const float*)d_in[11];
  const float* W1   = (const float*)d_in[12];
  const float* b1   = (const float*)d_in[13];
  const float* W2   = (const float*)d_in[14];
  const float* b2   = (const float*)d_in[15];

  char* ws = (char*)d_ws;
  size_t off = 0;
  auto alloc = [&](size_t bytes) {
    void* p = ws + off;
    off = (off + bytes + 255) & ~(size_t)255;
    return p;
  };
  int* cnt     = (int*)alloc((size_t)NL_NN * 4);
  int* scn     = (int*)alloc((size_t)NL_NN * 4);
  int* btot    = (int*)alloc(SCAN_BLKS * 4);
  int* boff    = (int*)alloc(SCAN_BLKS * 4);
  int* rank    = (int*)alloc((size_t)TOTAL_E * 4);
  int* rowptr  = (int*)alloc((size_t)(NL_NN + 32) * 4);
  float* wsumg = (float*)alloc((size_t)NL_NN * 4);
  int* epr     = (int*)alloc((size_t)TOTAL_SLOTS * 16 + 256);  // 16B recs + pad
  unsigned short* out_pre = (unsigned short*)alloc((size_t)NL_NN * 32 * 2);
  float* gsum   = (float*)alloc(N_LAYERS * 32 * 4);
  float* gsumsq = (float*)alloc(N_LAYERS * 32 * 4);
  float* xpad   = (float*)alloc((size_t)N_NODES * 8 * 4);
  __hip_bfloat16* w1t = (__hip_bfloat16*)alloc((size_t)896 * 800 * 2);
  float* pbuf = (float*)alloc((size_t)NPAD * NGRP * 5 * 4);  // 5.6 MB partials
  unsigned short* hn = (unsigned short*)alloc((size_t)N_LAYERS * NPAD * 32 * 2);

  prep_kernel<<<PREP_BLKS, 1024, 0, stream>>>(ei, ew, x, W1, cnt, rank, wsumg,
                                              xpad, w1t, hn);
  scan_a<<<SCAN_BLKS, 1024, 0, stream>>>(cnt, scn, btot, gsum, gsumsq);
  scan_b<<<1, 512, 0, stream>>>(btot, boff);
  fill_kernel<<<FILL_BLKS, 1024, 0, stream>>>(ei, ew, scn, boff, rank, wsumg,
                                              xpad, rowptr, epr);
  attn_kernel<<<ATTN_BLKS, 256, 0, stream>>>(
      xpad, rowptr, epr, Wl, bl, Wr, br, We, att, cb, out_pre, gsum, gsumsq);
  norm_kernel<<<(NL_NN * 8) / 256, 256, 0, stream>>>(
      out_pre, gsum, gsumsq, gam, bet, hn);
  gemm1_kernel<<<G1_BLKS, 256, 0, stream>>>(
      (const short*)hn, (const short*)w1t, b1, W2, pbuf);
  gemm2r_kernel<<<(N_NODES * 5 + 255) / 256, 256, 0, stream>>>(
      pbuf, b2, (float*)d_out);
}